// Round 4
// baseline (2216.526 us; speedup 1.0000x reference)
//
#include <hip/hip_runtime.h>
#include <hip/hip_bf16.h>
#include <math.h>

#define B_    256
#define S_    50
#define I_    1024
#define H_    512
#define G3_   1536   // 3*H
#define SENT_ 512
#define DOC_  1024

typedef short bf16x8 __attribute__((ext_vector_type(8)));
typedef float f32x4 __attribute__((ext_vector_type(4)));

__device__ __forceinline__ float sigf(float x) { return 1.0f / (1.0f + __expf(-x)); }

// async global->LDS, 16B per lane. LDS dest = wave-uniform base + lane*16.
__device__ __forceinline__ void gload16(const void* g, void* l) {
  __builtin_amdgcn_global_load_lds((const __attribute__((address_space(1))) void*)g,
                                   (__attribute__((address_space(3))) void*)l, 16, 0, 0);
}

// ===========================================================================
// bf16 MFMA GEMM (m97 structure), 128x128 tile, BK=64 — unchanged from R2.
// ===========================================================================
__global__ __launch_bounds__(256) void mfma_xg(
    const __hip_bfloat16* __restrict__ x,
    const __hip_bfloat16* __restrict__ Wf, const float* __restrict__ bf_,
    const __hip_bfloat16* __restrict__ Wb, const float* __restrict__ bb_,
    __hip_bfloat16* __restrict__ xgf, __hip_bfloat16* __restrict__ xgb) {
  __shared__ __align__(16) short As[128 * 64];
  __shared__ __align__(16) short Ws[128 * 64];
  const int dir = blockIdx.z;
  const __hip_bfloat16* W = dir ? Wb : Wf;
  const float* bias = dir ? bb_ : bf_;
  __hip_bfloat16* out = dir ? xgb : xgf;
  const int tid = threadIdx.x;
  const int m0 = blockIdx.y * 128, n0 = blockIdx.x * 128;
  const int s = blockIdx.y >> 1, b_base = (blockIdx.y & 1) * 128;
  const int s_eff = dir ? (S_ - 1 - s) : s;
  const int lane = tid & 63, w = tid >> 6;
  const int moff = (w & 1) * 64, noff = (w >> 1) * 64;
  const int frow = lane & 15, quad = lane >> 4;
  const int rr = tid >> 3, gs = tid & 7;
  f32x4 acc[4][4] = {};
  for (int kc = 0; kc < I_; kc += 64) {
#pragma unroll
    for (int iss = 0; iss < 4; iss++) {
      int r = iss * 32 + rr;
      int col = kc + ((gs ^ (r & 7)) << 3);
      gload16(x + ((size_t)(b_base + r) * S_ + s_eff) * I_ + col, &As[(iss * 256 + w * 64) * 8]);
    }
#pragma unroll
    for (int iss = 0; iss < 4; iss++) {
      int r = iss * 32 + rr;
      int col = kc + ((gs ^ (r & 7)) << 3);
      gload16(W + (size_t)(n0 + r) * I_ + col, &Ws[(iss * 256 + w * 64) * 8]);
    }
    __syncthreads();
#pragma unroll
    for (int ks = 0; ks < 2; ks++) {
      int kg = ks * 4 + quad;
      bf16x8 af[4], bfr[4];
#pragma unroll
      for (int mf = 0; mf < 4; mf++) {
        int r = moff + mf * 16 + frow;
        af[mf] = *(const bf16x8*)&As[(r * 8 + (kg ^ (r & 7))) * 8];
      }
#pragma unroll
      for (int nf = 0; nf < 4; nf++) {
        int r = noff + nf * 16 + frow;
        bfr[nf] = *(const bf16x8*)&Ws[(r * 8 + (kg ^ (r & 7))) * 8];
      }
#pragma unroll
      for (int mf = 0; mf < 4; mf++)
#pragma unroll
        for (int nf = 0; nf < 4; nf++)
          acc[mf][nf] = __builtin_amdgcn_mfma_f32_16x16x32_bf16(af[mf], bfr[nf], acc[mf][nf], 0, 0, 0);
    }
    __syncthreads();
  }
#pragma unroll
  for (int mf = 0; mf < 4; mf++) {
    int rowb = m0 + moff + mf * 16 + quad * 4;
#pragma unroll
    for (int nf = 0; nf < 4; nf++) {
      int col = n0 + noff + nf * 16 + frow;
      float bv = bias[col];
      f32x4 c = acc[mf][nf];
#pragma unroll
      for (int rg = 0; rg < 4; rg++)
        out[(size_t)(rowb + rg) * G3_ + col] = __float2bfloat16(c[rg] + bv);
    }
  }
}

template <int ACT, bool HASBIAS>
__global__ __launch_bounds__(256) void mfma_nt(
    const __hip_bfloat16* __restrict__ A, const __hip_bfloat16* __restrict__ W,
    const float* __restrict__ bias, __hip_bfloat16* __restrict__ outb, int N, int K) {
  __shared__ __align__(16) short As[128 * 64];
  __shared__ __align__(16) short Ws[128 * 64];
  const int tid = threadIdx.x;
  const int m0 = blockIdx.y * 128, n0 = blockIdx.x * 128;
  const int lane = tid & 63, w = tid >> 6;
  const int moff = (w & 1) * 64, noff = (w >> 1) * 64;
  const int frow = lane & 15, quad = lane >> 4;
  const int rr = tid >> 3, gs = tid & 7;
  f32x4 acc[4][4] = {};
  for (int kc = 0; kc < K; kc += 64) {
#pragma unroll
    for (int iss = 0; iss < 4; iss++) {
      int r = iss * 32 + rr;
      int col = kc + ((gs ^ (r & 7)) << 3);
      gload16(A + (size_t)(m0 + r) * K + col, &As[(iss * 256 + w * 64) * 8]);
    }
#pragma unroll
    for (int iss = 0; iss < 4; iss++) {
      int r = iss * 32 + rr;
      int col = kc + ((gs ^ (r & 7)) << 3);
      gload16(W + (size_t)(n0 + r) * K + col, &Ws[(iss * 256 + w * 64) * 8]);
    }
    __syncthreads();
#pragma unroll
    for (int ks = 0; ks < 2; ks++) {
      int kg = ks * 4 + quad;
      bf16x8 af[4], bfr[4];
#pragma unroll
      for (int mf = 0; mf < 4; mf++) {
        int r = moff + mf * 16 + frow;
        af[mf] = *(const bf16x8*)&As[(r * 8 + (kg ^ (r & 7))) * 8];
      }
#pragma unroll
      for (int nf = 0; nf < 4; nf++) {
        int r = noff + nf * 16 + frow;
        bfr[nf] = *(const bf16x8*)&Ws[(r * 8 + (kg ^ (r & 7))) * 8];
      }
#pragma unroll
      for (int mf = 0; mf < 4; mf++)
#pragma unroll
        for (int nf = 0; nf < 4; nf++)
          acc[mf][nf] = __builtin_amdgcn_mfma_f32_16x16x32_bf16(af[mf], bfr[nf], acc[mf][nf], 0, 0, 0);
    }
    __syncthreads();
  }
#pragma unroll
  for (int mf = 0; mf < 4; mf++) {
    int rowb = m0 + moff + mf * 16 + quad * 4;
#pragma unroll
    for (int nf = 0; nf < 4; nf++) {
      int col = n0 + noff + nf * 16 + frow;
      float bv = HASBIAS ? bias[col] : 0.f;
      f32x4 c = acc[mf][nf];
#pragma unroll
      for (int rg = 0; rg < 4; rg++) {
        float v = c[rg] + bv;
        if (ACT == 1) v = fmaxf(v, 0.f);
        outb[(size_t)(rowb + rg) * N + col] = __float2bfloat16(v);
      }
    }
  }
}

// ---------------------------------------------------------------------------
// Persistent GRU scan. REGULAR launch, grid 256 = 2 dir x 4 btile x 32 jslice,
// 1 block/CU (LDS=0, __launch_bounds__(256,1)) -> all 256 blocks co-resident
// on the idle device. Per-group (32-block) monotone-counter barrier with
// agent-scope atomics (G16 pattern) + bounded spin (timeout -> no hang).
// W_hh frags persist in ~192 VGPRs; lane's own h(t) fp32 in 4 VGPRs.
// ---------------------------------------------------------------------------
__global__ __launch_bounds__(256, 1) void gru_persistent(
    const __hip_bfloat16* __restrict__ xgf, const __hip_bfloat16* __restrict__ xgb,
    const __hip_bfloat16* __restrict__ Wpf, const __hip_bfloat16* __restrict__ Wpb,
    const float* __restrict__ bhhf, const float* __restrict__ bhhb,
    __hip_bfloat16* __restrict__ h16a, __hip_bfloat16* __restrict__ h16b,
    __hip_bfloat16* __restrict__ rnn,
    unsigned int* __restrict__ bar_cnt, unsigned int* __restrict__ bar_sense) {
  const int bid = blockIdx.x;
  const int dir = bid >> 7;
  const int bt = (bid >> 5) & 3;
  const int jt = bid & 31;
  const int g8 = bid >> 5;  // dir*4 + bt
  const int tid = threadIdx.x;
  const int w = tid >> 6, lane = tid & 63;
  const int frow = lane & 15, quad = lane >> 4;
  const __hip_bfloat16* xg = dir ? xgb : xgf;
  const __hip_bfloat16* Wp = dir ? Wpb : Wpf;
  const float* bhh = dir ? bhhb : bhhf;

  const int j = jt * 16 + frow;
  const int brow0 = bt * 64 + w * 16 + quad * 4;  // first of this lane's 4 b rows
  const float br = bhh[j], bz = bhh[H_ + j], bn = bhh[2 * H_ + j];

  // persistent W_hh fragments: 3 gates x 16 ksteps (192 VGPRs)
  bf16x8 wf[3][16];
#pragma unroll
  for (int g = 0; g < 3; g++)
#pragma unroll
    for (int ks = 0; ks < 16; ks++)
      wf[g][ks] = *(const bf16x8*)(Wp + (size_t)(jt * 48 + g * 16 + frow) * H_ + ks * 32 + quad * 8);

  float hreg[4] = {0.f, 0.f, 0.f, 0.f};

  for (int t = 0; t < S_; t++) {
    const __hip_bfloat16* hp = (t & 1) ? h16b : h16a;
    __hip_bfloat16* hn = (t & 1) ? h16a : h16b;
    // xg(t) for this lane's 4 rows / 3 gates
    float xgv[4][3];
#pragma unroll
    for (int rg = 0; rg < 4; rg++) {
      const __hip_bfloat16* xr = xg + ((size_t)t * B_ + brow0 + rg) * G3_;
      xgv[rg][0] = __bfloat162float(xr[j]);
      xgv[rg][1] = __bfloat162float(xr[H_ + j]);
      xgv[rg][2] = __bfloat162float(xr[2 * H_ + j]);
    }
    // A-frags: h(t) rows this wave owns (m = bt*64 + w*16 + frow), all K
    const __hip_bfloat16* hprow = hp + (size_t)(dir * B_ + bt * 64 + w * 16 + frow) * H_;
    bf16x8 af[16];
#pragma unroll
    for (int ks = 0; ks < 16; ks++) af[ks] = *(const bf16x8*)(hprow + ks * 32 + quad * 8);
    f32x4 acc[3] = {};
#pragma unroll
    for (int ks = 0; ks < 16; ks++)
#pragma unroll
      for (int g = 0; g < 3; g++)
        acc[g] = __builtin_amdgcn_mfma_f32_16x16x32_bf16(af[ks], wf[g][ks], acc[g], 0, 0, 0);

    const int s_orig = dir ? (S_ - 1 - t) : t;
#pragma unroll
    for (int rg = 0; rg < 4; rg++) {
      int b = brow0 + rg;
      float r = sigf(xgv[rg][0] + acc[0][rg] + br);
      float z = sigf(xgv[rg][1] + acc[1][rg] + bz);
      float n = tanhf(xgv[rg][2] + r * (acc[2][rg] + bn));
      float h = (1.f - z) * n + z * hreg[rg];
      hreg[rg] = h;
      __hip_bfloat16 hb = __float2bfloat16(h);
      hn[(size_t)(dir * B_ + b) * H_ + j] = hb;
      rnn[((size_t)b * S_ + s_orig) * (2 * H_) + dir * H_ + j] = hb;
    }

    if (t + 1 < S_) {
      __syncthreads();  // all lanes' hn stores issued (+ vmcnt drained by compiler)
      if (tid == 0) {
        __threadfence();  // release: make hn visible at device scope
        unsigned arr = __hip_atomic_fetch_add(&bar_cnt[g8], 1u, __ATOMIC_ACQ_REL,
                                              __HIP_MEMORY_SCOPE_AGENT);
        if (arr == 31u) {
          __hip_atomic_store(&bar_cnt[g8], 0u, __ATOMIC_RELAXED, __HIP_MEMORY_SCOPE_AGENT);
          __hip_atomic_store(&bar_sense[g8], (unsigned)(t + 1), __ATOMIC_RELEASE,
                             __HIP_MEMORY_SCOPE_AGENT);
        } else {
          // bounded spin: ~40 ms worst case, then proceed (no-hang safety valve)
          for (int spin = 0; spin < (1 << 17); spin++) {
            if (__hip_atomic_load(&bar_sense[g8], __ATOMIC_ACQUIRE,
                                  __HIP_MEMORY_SCOPE_AGENT) >= (unsigned)(t + 1))
              break;
            __builtin_amdgcn_s_sleep(2);
          }
        }
        __threadfence();  // acquire side for the whole block's subsequent loads
      }
      __syncthreads();
    }
  }
}

// ---------------------------------------------------------------------------
// fp32 tiled GEMM (small doc GEMMs)
// ---------------------------------------------------------------------------
template <int ACT>
__global__ __launch_bounds__(256) void gemm_nt(const float* __restrict__ A,
                                               const float* __restrict__ W,
                                               const float* __restrict__ bias,
                                               float* __restrict__ C, int N, int K) {
  __shared__ float As[16][68];
  __shared__ float Bs[16][68];
  const int t = threadIdx.x;
  const int tx = t & 15, ty = t >> 4;
  const int m0 = blockIdx.y * 64, n0 = blockIdx.x * 64;
  const int lr = t >> 2, lc = t & 3;
  const float* Arow = A + (size_t)(m0 + lr) * K;
  const float* Wrow = W + (size_t)(n0 + lr) * K;
  float acc[4][4] = {};
  for (int kc = 0; kc < K; kc += 16) {
    float4 av = *(const float4*)(Arow + kc + lc * 4);
    float4 wv = *(const float4*)(Wrow + kc + lc * 4);
    As[lc * 4 + 0][lr] = av.x; As[lc * 4 + 1][lr] = av.y;
    As[lc * 4 + 2][lr] = av.z; As[lc * 4 + 3][lr] = av.w;
    Bs[lc * 4 + 0][lr] = wv.x; Bs[lc * 4 + 1][lr] = wv.y;
    Bs[lc * 4 + 2][lr] = wv.z; Bs[lc * 4 + 3][lr] = wv.w;
    __syncthreads();
#pragma unroll
    for (int k = 0; k < 16; k++) {
      float4 a4 = *(const float4*)&As[k][ty * 4];
      float4 b4 = *(const float4*)&Bs[k][tx * 4];
      float ar[4] = {a4.x, a4.y, a4.z, a4.w};
      float br[4] = {b4.x, b4.y, b4.z, b4.w};
#pragma unroll
      for (int i = 0; i < 4; i++)
#pragma unroll
        for (int jx = 0; jx < 4; jx++) acc[i][jx] = fmaf(ar[i], br[jx], acc[i][jx]);
    }
    __syncthreads();
  }
  float4 bv = *(const float4*)&bias[n0 + tx * 4];
  float bb[4] = {bv.x, bv.y, bv.z, bv.w};
#pragma unroll
  for (int i = 0; i < 4; i++) {
    float o[4];
#pragma unroll
    for (int jx = 0; jx < 4; jx++) {
      float v = acc[i][jx] + bb[jx];
      if (ACT == 1) v = fmaxf(v, 0.f);
      if (ACT == 2) v = tanhf(v);
      o[jx] = v;
    }
    *(float4*)&C[(size_t)(m0 + ty * 4 + i) * N + n0 + tx * 4] = float4{o[0], o[1], o[2], o[3]};
  }
}

// ------------------------- small helper kernels ----------------------------
__global__ void cast_kernel(const float* __restrict__ in, __hip_bfloat16* __restrict__ out, int n) {
  int i = (blockIdx.x * blockDim.x + threadIdx.x) * 4;
  if (i + 3 < n) {
    float4 v = *(const float4*)(in + i);
    out[i + 0] = __float2bfloat16(v.x);
    out[i + 1] = __float2bfloat16(v.y);
    out[i + 2] = __float2bfloat16(v.z);
    out[i + 3] = __float2bfloat16(v.w);
  }
}

// pack W_hh: row p = (j>>4)*48 + g*16 + (j&15)  (16-j slices, 3 gates each)
__global__ void pack_whh(const float* __restrict__ Whh, __hip_bfloat16* __restrict__ outp) {
  int idx = blockIdx.x * 256 + threadIdx.x;
  if (idx >= G3_ * H_) return;
  int k = idx & 511;
  int row = idx >> 9;  // g*512 + j
  int g = row >> 9, j = row & 511;
  int p = (j >> 4) * 48 + g * 16 + (j & 15);
  outp[(size_t)p * H_ + k] = __float2bfloat16(Whh[idx]);
}

__global__ void tcast_wsim(const float* __restrict__ Wsim, __hip_bfloat16* __restrict__ outT) {
  int idx = blockIdx.x * 256 + threadIdx.x;
  if (idx >= SENT_ * SENT_) return;
  int i = idx >> 9, j = idx & 511;
  outT[(size_t)j * SENT_ + i] = __float2bfloat16(Wsim[idx]);
}

__global__ __launch_bounds__(256) void avg_kernel(const __hip_bfloat16* __restrict__ sent,
                                                  const int* __restrict__ ns,
                                                  float* __restrict__ avg) {
  int b = blockIdx.x, tid = threadIdx.x;
  const __hip_bfloat16* base = sent + (size_t)b * S_ * SENT_;
  float a0 = 0.f, a1 = 0.f;
  for (int s = 0; s < S_; s++) {
    a0 += __bfloat162float(base[s * SENT_ + tid]);
    a1 += __bfloat162float(base[s * SENT_ + 256 + tid]);
  }
  float inv = 1.0f / (float)ns[b];
  avg[(size_t)b * SENT_ + tid] = a0 * inv;
  avg[(size_t)b * SENT_ + 256 + tid] = a1 * inv;
}

__global__ void posseg_kernel(const float* __restrict__ pos_emb, const float* __restrict__ pos_lin,
                              const float* __restrict__ seg_emb, const float* __restrict__ seg_lin,
                              float* __restrict__ pos_logits, float* __restrict__ seg_vals) {
  int tid = threadIdx.x;
  if (tid < S_) {
    int idx = tid + 1; if (idx > 25) idx = 25;
    float a = 0.f;
    for (int k = 0; k < 50; k++) a += pos_emb[idx * 50 + k] * pos_lin[k];
    pos_logits[tid] = a;
  }
  if (tid < 5) {
    float a = 0.f;
    for (int k = 0; k < 50; k++) a += seg_emb[tid * 50 + k] * seg_lin[k];
    seg_vals[tid] = a;
  }
}

__global__ __launch_bounds__(64) void static_kernel(
    const __hip_bfloat16* __restrict__ sent, const float* __restrict__ doc,
    const float* __restrict__ wcont, const float* __restrict__ bcont,
    const int* __restrict__ ns, const float* __restrict__ pos_logits,
    const float* __restrict__ seg_vals, const float* __restrict__ bias,
    float* __restrict__ st) {
  int bs = blockIdx.x;
  int b = bs / S_, s = bs % S_;
  int lane = threadIdx.x;
  const __hip_bfloat16* sr = sent + (size_t)bs * SENT_;
  const float* dr = doc + (size_t)b * SENT_;
  float a0 = 0.f, a1 = 0.f;
#pragma unroll
  for (int ii = 0; ii < 8; ii++) {
    int k = ii * 64 + lane;
    float v = __bfloat162float(sr[k]);
    a0 += v * wcont[k];
    a1 += v * dr[k];
  }
#pragma unroll
  for (int off = 32; off; off >>= 1) {
    a0 += __shfl_down(a0, off);
    a1 += __shfl_down(a1, off);
  }
  if (lane == 0) {
    float chunk = rintf((float)ns[b] * 0.25f);
    float relf = ceilf((float)(s + 1) / chunk);
    relf = fminf(fmaxf(relf, 0.f), 4.f);
    int rel = (int)relf;
    st[s * B_ + b] = a0 + bcont[0] + a1 + pos_logits[s] + seg_vals[rel] + bias[0];
  }
}

__global__ __launch_bounds__(256) void novelty_all(
    const __hip_bfloat16* __restrict__ sent, const __hip_bfloat16* __restrict__ U,
    const float* __restrict__ st, float* __restrict__ out) {
  __shared__ float wred[4];
  int b = blockIdx.x, tid = threadIdx.x;
  float s0 = 0.f, s1 = 0.f;
  for (int t = 0; t < S_; t++) {
    const __hip_bfloat16* ur = U + ((size_t)b * S_ + t) * SENT_;
    float p = __bfloat162float(ur[tid]) * tanhf(s0) +
              __bfloat162float(ur[tid + 256]) * tanhf(s1);
#pragma unroll
    for (int off = 32; off; off >>= 1) p += __shfl_down(p, off);
    if ((tid & 63) == 0) wred[tid >> 6] = p;
    __syncthreads();
    float sim = wred[0] + wred[1] + wred[2] + wred[3];
    float logit = st[t * B_ + b] - sim;
    if (tid == 0) out[(size_t)t * B_ + b] = logit;
    float sg = sigf(logit);
    const __hip_bfloat16* sr = sent + ((size_t)b * S_ + t) * SENT_;
    s0 += __bfloat162float(sr[tid]) * sg;
    s1 += __bfloat162float(sr[tid + 256]) * sg;
    __syncthreads();
  }
}

extern "C" void kernel_launch(void* const* d_in, const int* in_sizes, int n_in,
                              void* d_out, int out_size, void* d_ws, size_t ws_size,
                              hipStream_t stream) {
  const float* x = (const float*)d_in[0];
  const int* ns = (const int*)d_in[1];
  const float* Wihf = (const float*)d_in[2];
  const float* Whhf = (const float*)d_in[3];
  const float* bihf = (const float*)d_in[4];
  const float* bhhf = (const float*)d_in[5];
  const float* Wihb = (const float*)d_in[6];
  const float* Whhb = (const float*)d_in[7];
  const float* bihb = (const float*)d_in[8];
  const float* bhhb = (const float*)d_in[9];
  const float* Wsent = (const float*)d_in[10];
  const float* bsent = (const float*)d_in[11];
  const float* wcont = (const float*)d_in[12];
  const float* bcont = (const float*)d_in[13];
  const float* Wd1 = (const float*)d_in[14];
  const float* bd1 = (const float*)d_in[15];
  const float* Wd2 = (const float*)d_in[16];
  const float* bd2 = (const float*)d_in[17];
  const float* Wsim = (const float*)d_in[18];
  const float* bias = (const float*)d_in[19];
  const float* pos_emb = (const float*)d_in[20];
  const float* pos_lin = (const float*)d_in[21];
  const float* seg_emb = (const float*)d_in[22];
  const float* seg_lin = (const float*)d_in[23];
  float* out = (float*)d_out;

  char* base = (char*)d_ws;
  size_t off = 0;
  auto alloc = [&](size_t bytes) { char* p = base + off; off += (bytes + 255) & ~255ull; return p; };
  __hip_bfloat16* xgf_b  = (__hip_bfloat16*)alloc((size_t)S_ * B_ * G3_ * 2);
  __hip_bfloat16* xgb_b  = (__hip_bfloat16*)alloc((size_t)S_ * B_ * G3_ * 2);
  char* region1          = alloc((size_t)B_ * S_ * I_ * 2);  // x_bf, later sent_b+U_b
  __hip_bfloat16* x_bf   = (__hip_bfloat16*)region1;
  __hip_bfloat16* sent_b = (__hip_bfloat16*)region1;
  __hip_bfloat16* U_b    = (__hip_bfloat16*)(region1 + (size_t)B_ * S_ * SENT_ * 2);
  __hip_bfloat16* rnn_b  = (__hip_bfloat16*)alloc((size_t)B_ * S_ * 2 * H_ * 2);
  __hip_bfloat16* Wihf_b = (__hip_bfloat16*)alloc((size_t)G3_ * I_ * 2);
  __hip_bfloat16* Wihb_b = (__hip_bfloat16*)alloc((size_t)G3_ * I_ * 2);
  __hip_bfloat16* Wpf    = (__hip_bfloat16*)alloc((size_t)G3_ * H_ * 2);
  __hip_bfloat16* Wpb    = (__hip_bfloat16*)alloc((size_t)G3_ * H_ * 2);
  __hip_bfloat16* Wsent_b= (__hip_bfloat16*)alloc((size_t)SENT_ * 2 * H_ * 2);
  __hip_bfloat16* WsimT_b= (__hip_bfloat16*)alloc((size_t)SENT_ * SENT_ * 2);
  __hip_bfloat16* h16a   = (__hip_bfloat16*)alloc(2 * (size_t)B_ * H_ * 2);  // [dir][B][H]
  __hip_bfloat16* h16b   = (__hip_bfloat16*)alloc(2 * (size_t)B_ * H_ * 2);
  unsigned int* bar_cnt  = (unsigned int*)alloc(32 * 4);
  unsigned int* bar_sense= (unsigned int*)alloc(32 * 4);
  float* avg             = (float*)alloc((size_t)B_ * SENT_ * 4);
  float* d1buf           = (float*)alloc((size_t)B_ * DOC_ * 4);
  float* doc             = (float*)alloc((size_t)B_ * SENT_ * 4);
  float* st              = (float*)alloc((size_t)S_ * B_ * 4);
  float* poslog          = (float*)alloc(256);
  float* segvals         = (float*)alloc(64);
  (void)ws_size;

  // zero h16a (t=0 state) and barrier counters/sense
  hipMemsetAsync(h16a, 0, 2 * (size_t)B_ * H_ * 2, stream);
  hipMemsetAsync(bar_cnt, 0, 512, stream);  // covers bar_cnt (256B-padded) + bar_sense

  cast_kernel<<<(B_ * S_ * I_ / 4 + 255) / 256, 256, 0, stream>>>(x, x_bf, B_ * S_ * I_);
  cast_kernel<<<(G3_ * I_ / 4 + 255) / 256, 256, 0, stream>>>(Wihf, Wihf_b, G3_ * I_);
  cast_kernel<<<(G3_ * I_ / 4 + 255) / 256, 256, 0, stream>>>(Wihb, Wihb_b, G3_ * I_);
  cast_kernel<<<(SENT_ * 2 * H_ / 4 + 255) / 256, 256, 0, stream>>>(Wsent, Wsent_b, SENT_ * 2 * H_);
  pack_whh<<<(G3_ * H_ + 255) / 256, 256, 0, stream>>>(Whhf, Wpf);
  pack_whh<<<(G3_ * H_ + 255) / 256, 256, 0, stream>>>(Whhb, Wpb);
  tcast_wsim<<<(SENT_ * SENT_ + 255) / 256, 256, 0, stream>>>(Wsim, WsimT_b);
  posseg_kernel<<<1, 64, 0, stream>>>(pos_emb, pos_lin, seg_emb, seg_lin, poslog, segvals);

  mfma_xg<<<dim3(G3_ / 128, (S_ * B_) / 128, 2), 256, 0, stream>>>(x_bf, Wihf_b, bihf, Wihb_b, bihb, xgf_b, xgb_b);

  // persistent GRU scan — regular launch; 256 blocks at 1 block/CU on an idle
  // device are co-resident; per-group hand-rolled barriers (agent scope).
  gru_persistent<<<dim3(256), dim3(256), 0, stream>>>(
      xgf_b, xgb_b, Wpf, Wpb, bhhf, bhhb, h16a, h16b, rnn_b, bar_cnt, bar_sense);

  mfma_nt<1, true><<<dim3(SENT_ / 128, (B_ * S_) / 128), 256, 0, stream>>>(rnn_b, Wsent_b, bsent, sent_b, SENT_, 2 * H_);
  avg_kernel<<<B_, 256, 0, stream>>>(sent_b, ns, avg);
  gemm_nt<2><<<dim3(DOC_ / 64, B_ / 64), 256, 0, stream>>>(avg, Wd1, bd1, d1buf, DOC_, SENT_);
  gemm_nt<0><<<dim3(SENT_ / 64, B_ / 64), 256, 0, stream>>>(d1buf, Wd2, bd2, doc, SENT_, DOC_);
  static_kernel<<<B_ * S_, 64, 0, stream>>>(sent_b, doc, wcont, bcont, ns, poslog, segvals, bias, st);

  mfma_nt<0, false><<<dim3(SENT_ / 128, (B_ * S_) / 128), 256, 0, stream>>>(sent_b, WsimT_b, nullptr, U_b, SENT_, SENT_);

  novelty_all<<<B_, 256, 0, stream>>>(sent_b, U_b, st, out);
}

// Round 6
// 1593.976 us; speedup vs baseline: 1.3906x; 1.3906x over previous
//
#include <hip/hip_runtime.h>
#include <hip/hip_bf16.h>
#include <math.h>

#define B_    256
#define S_    50
#define I_    1024
#define H_    512
#define G3_   1536   // 3*H
#define SENT_ 512
#define DOC_  1024

typedef short bf16x8 __attribute__((ext_vector_type(8)));
typedef float f32x4 __attribute__((ext_vector_type(4)));

__device__ __forceinline__ float sigf(float x) { return 1.0f / (1.0f + __expf(-x)); }

// async global->LDS, 16B per lane. LDS dest = wave-uniform base + lane*16.
__device__ __forceinline__ void gload16(const void* g, void* l) {
  __builtin_amdgcn_global_load_lds((const __attribute__((address_space(1))) void*)g,
                                   (__attribute__((address_space(3))) void*)l, 16, 0, 0);
}

// ===========================================================================
// bf16 MFMA GEMM (m97 structure), 128x128 tile, BK=64 — unchanged from R2.
// ===========================================================================
__global__ __launch_bounds__(256) void mfma_xg(
    const __hip_bfloat16* __restrict__ x,
    const __hip_bfloat16* __restrict__ Wf, const float* __restrict__ bf_,
    const __hip_bfloat16* __restrict__ Wb, const float* __restrict__ bb_,
    __hip_bfloat16* __restrict__ xgf, __hip_bfloat16* __restrict__ xgb) {
  __shared__ __align__(16) short As[128 * 64];
  __shared__ __align__(16) short Ws[128 * 64];
  const int dir = blockIdx.z;
  const __hip_bfloat16* W = dir ? Wb : Wf;
  const float* bias = dir ? bb_ : bf_;
  __hip_bfloat16* out = dir ? xgb : xgf;
  const int tid = threadIdx.x;
  const int m0 = blockIdx.y * 128, n0 = blockIdx.x * 128;
  const int s = blockIdx.y >> 1, b_base = (blockIdx.y & 1) * 128;
  const int s_eff = dir ? (S_ - 1 - s) : s;
  const int lane = tid & 63, w = tid >> 6;
  const int moff = (w & 1) * 64, noff = (w >> 1) * 64;
  const int frow = lane & 15, quad = lane >> 4;
  const int rr = tid >> 3, gs = tid & 7;
  f32x4 acc[4][4] = {};
  for (int kc = 0; kc < I_; kc += 64) {
#pragma unroll
    for (int iss = 0; iss < 4; iss++) {
      int r = iss * 32 + rr;
      int col = kc + ((gs ^ (r & 7)) << 3);
      gload16(x + ((size_t)(b_base + r) * S_ + s_eff) * I_ + col, &As[(iss * 256 + w * 64) * 8]);
    }
#pragma unroll
    for (int iss = 0; iss < 4; iss++) {
      int r = iss * 32 + rr;
      int col = kc + ((gs ^ (r & 7)) << 3);
      gload16(W + (size_t)(n0 + r) * I_ + col, &Ws[(iss * 256 + w * 64) * 8]);
    }
    __syncthreads();
#pragma unroll
    for (int ks = 0; ks < 2; ks++) {
      int kg = ks * 4 + quad;
      bf16x8 af[4], bfr[4];
#pragma unroll
      for (int mf = 0; mf < 4; mf++) {
        int r = moff + mf * 16 + frow;
        af[mf] = *(const bf16x8*)&As[(r * 8 + (kg ^ (r & 7))) * 8];
      }
#pragma unroll
      for (int nf = 0; nf < 4; nf++) {
        int r = noff + nf * 16 + frow;
        bfr[nf] = *(const bf16x8*)&Ws[(r * 8 + (kg ^ (r & 7))) * 8];
      }
#pragma unroll
      for (int mf = 0; mf < 4; mf++)
#pragma unroll
        for (int nf = 0; nf < 4; nf++)
          acc[mf][nf] = __builtin_amdgcn_mfma_f32_16x16x32_bf16(af[mf], bfr[nf], acc[mf][nf], 0, 0, 0);
    }
    __syncthreads();
  }
#pragma unroll
  for (int mf = 0; mf < 4; mf++) {
    int rowb = m0 + moff + mf * 16 + quad * 4;
#pragma unroll
    for (int nf = 0; nf < 4; nf++) {
      int col = n0 + noff + nf * 16 + frow;
      float bv = bias[col];
      f32x4 c = acc[mf][nf];
#pragma unroll
      for (int rg = 0; rg < 4; rg++)
        out[(size_t)(rowb + rg) * G3_ + col] = __float2bfloat16(c[rg] + bv);
    }
  }
}

template <int ACT, bool HASBIAS>
__global__ __launch_bounds__(256) void mfma_nt(
    const __hip_bfloat16* __restrict__ A, const __hip_bfloat16* __restrict__ W,
    const float* __restrict__ bias, __hip_bfloat16* __restrict__ outb, int N, int K) {
  __shared__ __align__(16) short As[128 * 64];
  __shared__ __align__(16) short Ws[128 * 64];
  const int tid = threadIdx.x;
  const int m0 = blockIdx.y * 128, n0 = blockIdx.x * 128;
  const int lane = tid & 63, w = tid >> 6;
  const int moff = (w & 1) * 64, noff = (w >> 1) * 64;
  const int frow = lane & 15, quad = lane >> 4;
  const int rr = tid >> 3, gs = tid & 7;
  f32x4 acc[4][4] = {};
  for (int kc = 0; kc < K; kc += 64) {
#pragma unroll
    for (int iss = 0; iss < 4; iss++) {
      int r = iss * 32 + rr;
      int col = kc + ((gs ^ (r & 7)) << 3);
      gload16(A + (size_t)(m0 + r) * K + col, &As[(iss * 256 + w * 64) * 8]);
    }
#pragma unroll
    for (int iss = 0; iss < 4; iss++) {
      int r = iss * 32 + rr;
      int col = kc + ((gs ^ (r & 7)) << 3);
      gload16(W + (size_t)(n0 + r) * K + col, &Ws[(iss * 256 + w * 64) * 8]);
    }
    __syncthreads();
#pragma unroll
    for (int ks = 0; ks < 2; ks++) {
      int kg = ks * 4 + quad;
      bf16x8 af[4], bfr[4];
#pragma unroll
      for (int mf = 0; mf < 4; mf++) {
        int r = moff + mf * 16 + frow;
        af[mf] = *(const bf16x8*)&As[(r * 8 + (kg ^ (r & 7))) * 8];
      }
#pragma unroll
      for (int nf = 0; nf < 4; nf++) {
        int r = noff + nf * 16 + frow;
        bfr[nf] = *(const bf16x8*)&Ws[(r * 8 + (kg ^ (r & 7))) * 8];
      }
#pragma unroll
      for (int mf = 0; mf < 4; mf++)
#pragma unroll
        for (int nf = 0; nf < 4; nf++)
          acc[mf][nf] = __builtin_amdgcn_mfma_f32_16x16x32_bf16(af[mf], bfr[nf], acc[mf][nf], 0, 0, 0);
    }
    __syncthreads();
  }
#pragma unroll
  for (int mf = 0; mf < 4; mf++) {
    int rowb = m0 + moff + mf * 16 + quad * 4;
#pragma unroll
    for (int nf = 0; nf < 4; nf++) {
      int col = n0 + noff + nf * 16 + frow;
      float bv = HASBIAS ? bias[col] : 0.f;
      f32x4 c = acc[mf][nf];
#pragma unroll
      for (int rg = 0; rg < 4; rg++) {
        float v = c[rg] + bv;
        if (ACT == 1) v = fmaxf(v, 0.f);
        outb[(size_t)(rowb + rg) * N + col] = __float2bfloat16(v);
      }
    }
  }
}

// ---------------------------------------------------------------------------
// Persistent GRU scan (regular launch, 256 blocks, 1 block/CU).
// Barrier design (R5 theory, fence spelling fixed):
//  - per-group cnt/sense in their OWN 256B slots (no shared-cacheline storm)
//  - waiters poll with RELAXED atomic loads (no buffer_inv per poll), then
//    ONE acquire fence (__builtin_amdgcn_fence) after barrier exit.
//    R4's acquire-load polls invalidated the XCD L2 every iteration.
// ---------------------------------------------------------------------------
__global__ __launch_bounds__(256, 1) void gru_persistent(
    const __hip_bfloat16* __restrict__ xgf, const __hip_bfloat16* __restrict__ xgb,
    const __hip_bfloat16* __restrict__ Wpf, const __hip_bfloat16* __restrict__ Wpb,
    const float* __restrict__ bhhf, const float* __restrict__ bhhb,
    __hip_bfloat16* __restrict__ h16a, __hip_bfloat16* __restrict__ h16b,
    __hip_bfloat16* __restrict__ rnn,
    unsigned int* __restrict__ bar_cnt, unsigned int* __restrict__ bar_sense) {
  const int bid = blockIdx.x;
  const int dir = bid >> 7;
  const int bt = (bid >> 5) & 3;
  const int jt = bid & 31;
  const int g8 = bid >> 5;  // dir*4 + bt
  const int tid = threadIdx.x;
  const int w = tid >> 6, lane = tid & 63;
  const int frow = lane & 15, quad = lane >> 4;
  const __hip_bfloat16* xg = dir ? xgb : xgf;
  const __hip_bfloat16* Wp = dir ? Wpb : Wpf;
  const float* bhh = dir ? bhhb : bhhf;

  unsigned int* cnt = bar_cnt + g8 * 64;    // 256B-strided slot per group
  unsigned int* sense = bar_sense + g8 * 64;

  const int j = jt * 16 + frow;
  const int brow0 = bt * 64 + w * 16 + quad * 4;  // first of this lane's 4 b rows
  const float br = bhh[j], bz = bhh[H_ + j], bn = bhh[2 * H_ + j];

  // persistent W_hh fragments: 3 gates x 16 ksteps (192 VGPRs)
  bf16x8 wf[3][16];
#pragma unroll
  for (int g = 0; g < 3; g++)
#pragma unroll
    for (int ks = 0; ks < 16; ks++)
      wf[g][ks] = *(const bf16x8*)(Wp + (size_t)(jt * 48 + g * 16 + frow) * H_ + ks * 32 + quad * 8);

  float hreg[4] = {0.f, 0.f, 0.f, 0.f};

  for (int t = 0; t < S_; t++) {
    const __hip_bfloat16* hp = (t & 1) ? h16b : h16a;
    __hip_bfloat16* hn = (t & 1) ? h16a : h16b;
    // xg(t) for this lane's 4 rows / 3 gates
    float xgv[4][3];
#pragma unroll
    for (int rg = 0; rg < 4; rg++) {
      const __hip_bfloat16* xr = xg + ((size_t)t * B_ + brow0 + rg) * G3_;
      xgv[rg][0] = __bfloat162float(xr[j]);
      xgv[rg][1] = __bfloat162float(xr[H_ + j]);
      xgv[rg][2] = __bfloat162float(xr[2 * H_ + j]);
    }
    // A-frags: h(t) rows this wave owns (m = bt*64 + w*16 + frow), all K
    const __hip_bfloat16* hprow = hp + (size_t)(dir * B_ + bt * 64 + w * 16 + frow) * H_;
    bf16x8 af[16];
#pragma unroll
    for (int ks = 0; ks < 16; ks++) af[ks] = *(const bf16x8*)(hprow + ks * 32 + quad * 8);
    f32x4 acc[3] = {};
#pragma unroll
    for (int ks = 0; ks < 16; ks++)
#pragma unroll
      for (int g = 0; g < 3; g++)
        acc[g] = __builtin_amdgcn_mfma_f32_16x16x32_bf16(af[ks], wf[g][ks], acc[g], 0, 0, 0);

    const int s_orig = dir ? (S_ - 1 - t) : t;
#pragma unroll
    for (int rg = 0; rg < 4; rg++) {
      int b = brow0 + rg;
      float r = sigf(xgv[rg][0] + acc[0][rg] + br);
      float z = sigf(xgv[rg][1] + acc[1][rg] + bz);
      float n = tanhf(xgv[rg][2] + r * (acc[2][rg] + bn));
      float h = (1.f - z) * n + z * hreg[rg];
      hreg[rg] = h;
      __hip_bfloat16 hb = __float2bfloat16(h);
      hn[(size_t)(dir * B_ + b) * H_ + j] = hb;
      rnn[((size_t)b * S_ + s_orig) * (2 * H_) + dir * H_ + j] = hb;
    }

    if (t + 1 < S_) {
      __syncthreads();  // all lanes' hn stores issued
      if (tid == 0) {
        // release: drain vm + write back L2 before signaling
        __builtin_amdgcn_fence(__ATOMIC_RELEASE, "agent");
        unsigned arr = __hip_atomic_fetch_add(cnt, 1u, __ATOMIC_ACQ_REL,
                                              __HIP_MEMORY_SCOPE_AGENT);
        if (arr == 31u) {
          __hip_atomic_store(cnt, 0u, __ATOMIC_RELAXED, __HIP_MEMORY_SCOPE_AGENT);
          __hip_atomic_store(sense, (unsigned)(t + 1), __ATOMIC_RELEASE,
                             __HIP_MEMORY_SCOPE_AGENT);
        } else {
          // RELAXED polls: visibility without per-poll cache invalidation.
          for (int spin = 0; spin < (1 << 17); spin++) {
            if (__hip_atomic_load(sense, __ATOMIC_RELAXED,
                                  __HIP_MEMORY_SCOPE_AGENT) >= (unsigned)(t + 1))
              break;
            __builtin_amdgcn_s_sleep(8);
          }
        }
        // single acquire per step: invalidate stale L1/L2 before h reads
        __builtin_amdgcn_fence(__ATOMIC_ACQUIRE, "agent");
      }
      __syncthreads();
    }
  }
}

// ---------------------------------------------------------------------------
// fp32 tiled GEMM (small doc GEMMs)
// ---------------------------------------------------------------------------
template <int ACT>
__global__ __launch_bounds__(256) void gemm_nt(const float* __restrict__ A,
                                               const float* __restrict__ W,
                                               const float* __restrict__ bias,
                                               float* __restrict__ C, int N, int K) {
  __shared__ float As[16][68];
  __shared__ float Bs[16][68];
  const int t = threadIdx.x;
  const int tx = t & 15, ty = t >> 4;
  const int m0 = blockIdx.y * 64, n0 = blockIdx.x * 64;
  const int lr = t >> 2, lc = t & 3;
  const float* Arow = A + (size_t)(m0 + lr) * K;
  const float* Wrow = W + (size_t)(n0 + lr) * K;
  float acc[4][4] = {};
  for (int kc = 0; kc < K; kc += 16) {
    float4 av = *(const float4*)(Arow + kc + lc * 4);
    float4 wv = *(const float4*)(Wrow + kc + lc * 4);
    As[lc * 4 + 0][lr] = av.x; As[lc * 4 + 1][lr] = av.y;
    As[lc * 4 + 2][lr] = av.z; As[lc * 4 + 3][lr] = av.w;
    Bs[lc * 4 + 0][lr] = wv.x; Bs[lc * 4 + 1][lr] = wv.y;
    Bs[lc * 4 + 2][lr] = wv.z; Bs[lc * 4 + 3][lr] = wv.w;
    __syncthreads();
#pragma unroll
    for (int k = 0; k < 16; k++) {
      float4 a4 = *(const float4*)&As[k][ty * 4];
      float4 b4 = *(const float4*)&Bs[k][tx * 4];
      float ar[4] = {a4.x, a4.y, a4.z, a4.w};
      float br[4] = {b4.x, b4.y, b4.z, b4.w};
#pragma unroll
      for (int i = 0; i < 4; i++)
#pragma unroll
        for (int jx = 0; jx < 4; jx++) acc[i][jx] = fmaf(ar[i], br[jx], acc[i][jx]);
    }
    __syncthreads();
  }
  float4 bv = *(const float4*)&bias[n0 + tx * 4];
  float bb[4] = {bv.x, bv.y, bv.z, bv.w};
#pragma unroll
  for (int i = 0; i < 4; i++) {
    float o[4];
#pragma unroll
    for (int jx = 0; jx < 4; jx++) {
      float v = acc[i][jx] + bb[jx];
      if (ACT == 1) v = fmaxf(v, 0.f);
      if (ACT == 2) v = tanhf(v);
      o[jx] = v;
    }
    *(float4*)&C[(size_t)(m0 + ty * 4 + i) * N + n0 + tx * 4] = float4{o[0], o[1], o[2], o[3]};
  }
}

// ------------------------- small helper kernels ----------------------------
__global__ void cast_kernel(const float* __restrict__ in, __hip_bfloat16* __restrict__ out, int n) {
  int i = (blockIdx.x * blockDim.x + threadIdx.x) * 4;
  if (i + 3 < n) {
    float4 v = *(const float4*)(in + i);
    out[i + 0] = __float2bfloat16(v.x);
    out[i + 1] = __float2bfloat16(v.y);
    out[i + 2] = __float2bfloat16(v.z);
    out[i + 3] = __float2bfloat16(v.w);
  }
}

// pack W_hh: row p = (j>>4)*48 + g*16 + (j&15)  (16-j slices, 3 gates each)
__global__ void pack_whh(const float* __restrict__ Whh, __hip_bfloat16* __restrict__ outp) {
  int idx = blockIdx.x * 256 + threadIdx.x;
  if (idx >= G3_ * H_) return;
  int k = idx & 511;
  int row = idx >> 9;  // g*512 + j
  int g = row >> 9, j = row & 511;
  int p = (j >> 4) * 48 + g * 16 + (j & 15);
  outp[(size_t)p * H_ + k] = __float2bfloat16(Whh[idx]);
}

__global__ void tcast_wsim(const float* __restrict__ Wsim, __hip_bfloat16* __restrict__ outT) {
  int idx = blockIdx.x * 256 + threadIdx.x;
  if (idx >= SENT_ * SENT_) return;
  int i = idx >> 9, j = idx & 511;
  outT[(size_t)j * SENT_ + i] = __float2bfloat16(Wsim[idx]);
}

__global__ __launch_bounds__(256) void avg_kernel(const __hip_bfloat16* __restrict__ sent,
                                                  const int* __restrict__ ns,
                                                  float* __restrict__ avg) {
  int b = blockIdx.x, tid = threadIdx.x;
  const __hip_bfloat16* base = sent + (size_t)b * S_ * SENT_;
  float a0 = 0.f, a1 = 0.f;
  for (int s = 0; s < S_; s++) {
    a0 += __bfloat162float(base[s * SENT_ + tid]);
    a1 += __bfloat162float(base[s * SENT_ + 256 + tid]);
  }
  float inv = 1.0f / (float)ns[b];
  avg[(size_t)b * SENT_ + tid] = a0 * inv;
  avg[(size_t)b * SENT_ + 256 + tid] = a1 * inv;
}

__global__ void posseg_kernel(const float* __restrict__ pos_emb, const float* __restrict__ pos_lin,
                              const float* __restrict__ seg_emb, const float* __restrict__ seg_lin,
                              float* __restrict__ pos_logits, float* __restrict__ seg_vals) {
  int tid = threadIdx.x;
  if (tid < S_) {
    int idx = tid + 1; if (idx > 25) idx = 25;
    float a = 0.f;
    for (int k = 0; k < 50; k++) a += pos_emb[idx * 50 + k] * pos_lin[k];
    pos_logits[tid] = a;
  }
  if (tid < 5) {
    float a = 0.f;
    for (int k = 0; k < 50; k++) a += seg_emb[tid * 50 + k] * seg_lin[k];
    seg_vals[tid] = a;
  }
}

__global__ __launch_bounds__(64) void static_kernel(
    const __hip_bfloat16* __restrict__ sent, const float* __restrict__ doc,
    const float* __restrict__ wcont, const float* __restrict__ bcont,
    const int* __restrict__ ns, const float* __restrict__ pos_logits,
    const float* __restrict__ seg_vals, const float* __restrict__ bias,
    float* __restrict__ st) {
  int bs = blockIdx.x;
  int b = bs / S_, s = bs % S_;
  int lane = threadIdx.x;
  const __hip_bfloat16* sr = sent + (size_t)bs * SENT_;
  const float* dr = doc + (size_t)b * SENT_;
  float a0 = 0.f, a1 = 0.f;
#pragma unroll
  for (int ii = 0; ii < 8; ii++) {
    int k = ii * 64 + lane;
    float v = __bfloat162float(sr[k]);
    a0 += v * wcont[k];
    a1 += v * dr[k];
  }
#pragma unroll
  for (int off = 32; off; off >>= 1) {
    a0 += __shfl_down(a0, off);
    a1 += __shfl_down(a1, off);
  }
  if (lane == 0) {
    float chunk = rintf((float)ns[b] * 0.25f);
    float relf = ceilf((float)(s + 1) / chunk);
    relf = fminf(fmaxf(relf, 0.f), 4.f);
    int rel = (int)relf;
    st[s * B_ + b] = a0 + bcont[0] + a1 + pos_logits[s] + seg_vals[rel] + bias[0];
  }
}

__global__ __launch_bounds__(256) void novelty_all(
    const __hip_bfloat16* __restrict__ sent, const __hip_bfloat16* __restrict__ U,
    const float* __restrict__ st, float* __restrict__ out) {
  __shared__ float wred[4];
  int b = blockIdx.x, tid = threadIdx.x;
  float s0 = 0.f, s1 = 0.f;
  for (int t = 0; t < S_; t++) {
    const __hip_bfloat16* ur = U + ((size_t)b * S_ + t) * SENT_;
    float p = __bfloat162float(ur[tid]) * tanhf(s0) +
              __bfloat162float(ur[tid + 256]) * tanhf(s1);
#pragma unroll
    for (int off = 32; off; off >>= 1) p += __shfl_down(p, off);
    if ((tid & 63) == 0) wred[tid >> 6] = p;
    __syncthreads();
    float sim = wred[0] + wred[1] + wred[2] + wred[3];
    float logit = st[t * B_ + b] - sim;
    if (tid == 0) out[(size_t)t * B_ + b] = logit;
    float sg = sigf(logit);
    const __hip_bfloat16* sr = sent + ((size_t)b * S_ + t) * SENT_;
    s0 += __bfloat162float(sr[tid]) * sg;
    s1 += __bfloat162float(sr[tid + 256]) * sg;
    __syncthreads();
  }
}

extern "C" void kernel_launch(void* const* d_in, const int* in_sizes, int n_in,
                              void* d_out, int out_size, void* d_ws, size_t ws_size,
                              hipStream_t stream) {
  const float* x = (const float*)d_in[0];
  const int* ns = (const int*)d_in[1];
  const float* Wihf = (const float*)d_in[2];
  const float* Whhf = (const float*)d_in[3];
  const float* bihf = (const float*)d_in[4];
  const float* bhhf = (const float*)d_in[5];
  const float* Wihb = (const float*)d_in[6];
  const float* Whhb = (const float*)d_in[7];
  const float* bihb = (const float*)d_in[8];
  const float* bhhb = (const float*)d_in[9];
  const float* Wsent = (const float*)d_in[10];
  const float* bsent = (const float*)d_in[11];
  const float* wcont = (const float*)d_in[12];
  const float* bcont = (const float*)d_in[13];
  const float* Wd1 = (const float*)d_in[14];
  const float* bd1 = (const float*)d_in[15];
  const float* Wd2 = (const float*)d_in[16];
  const float* bd2 = (const float*)d_in[17];
  const float* Wsim = (const float*)d_in[18];
  const float* bias = (const float*)d_in[19];
  const float* pos_emb = (const float*)d_in[20];
  const float* pos_lin = (const float*)d_in[21];
  const float* seg_emb = (const float*)d_in[22];
  const float* seg_lin = (const float*)d_in[23];
  float* out = (float*)d_out;

  char* base = (char*)d_ws;
  size_t off = 0;
  auto alloc = [&](size_t bytes) { char* p = base + off; off += (bytes + 255) & ~255ull; return p; };
  __hip_bfloat16* xgf_b  = (__hip_bfloat16*)alloc((size_t)S_ * B_ * G3_ * 2);
  __hip_bfloat16* xgb_b  = (__hip_bfloat16*)alloc((size_t)S_ * B_ * G3_ * 2);
  char* region1          = alloc((size_t)B_ * S_ * I_ * 2);  // x_bf, later sent_b+U_b
  __hip_bfloat16* x_bf   = (__hip_bfloat16*)region1;
  __hip_bfloat16* sent_b = (__hip_bfloat16*)region1;
  __hip_bfloat16* U_b    = (__hip_bfloat16*)(region1 + (size_t)B_ * S_ * SENT_ * 2);
  __hip_bfloat16* rnn_b  = (__hip_bfloat16*)alloc((size_t)B_ * S_ * 2 * H_ * 2);
  __hip_bfloat16* Wihf_b = (__hip_bfloat16*)alloc((size_t)G3_ * I_ * 2);
  __hip_bfloat16* Wihb_b = (__hip_bfloat16*)alloc((size_t)G3_ * I_ * 2);
  __hip_bfloat16* Wpf    = (__hip_bfloat16*)alloc((size_t)G3_ * H_ * 2);
  __hip_bfloat16* Wpb    = (__hip_bfloat16*)alloc((size_t)G3_ * H_ * 2);
  __hip_bfloat16* Wsent_b= (__hip_bfloat16*)alloc((size_t)SENT_ * 2 * H_ * 2);
  __hip_bfloat16* WsimT_b= (__hip_bfloat16*)alloc((size_t)SENT_ * SENT_ * 2);
  __hip_bfloat16* h16a   = (__hip_bfloat16*)alloc(2 * (size_t)B_ * H_ * 2);  // [dir][B][H]
  __hip_bfloat16* h16b   = (__hip_bfloat16*)alloc(2 * (size_t)B_ * H_ * 2);
  unsigned int* bar_cnt  = (unsigned int*)alloc(8 * 64 * 4);   // 256B slot per group
  unsigned int* bar_sense= (unsigned int*)alloc(8 * 64 * 4);
  float* avg             = (float*)alloc((size_t)B_ * SENT_ * 4);
  float* d1buf           = (float*)alloc((size_t)B_ * DOC_ * 4);
  float* doc             = (float*)alloc((size_t)B_ * SENT_ * 4);
  float* st              = (float*)alloc((size_t)S_ * B_ * 4);
  float* poslog          = (float*)alloc(256);
  float* segvals         = (float*)alloc(64);
  (void)ws_size;

  // zero h16a (t=0 state) and barrier counters/sense (two contiguous 2KB slabs)
  (void)hipMemsetAsync(h16a, 0, 2 * (size_t)B_ * H_ * 2, stream);
  (void)hipMemsetAsync(bar_cnt, 0, 2 * 8 * 64 * 4, stream);

  cast_kernel<<<(B_ * S_ * I_ / 4 + 255) / 256, 256, 0, stream>>>(x, x_bf, B_ * S_ * I_);
  cast_kernel<<<(G3_ * I_ / 4 + 255) / 256, 256, 0, stream>>>(Wihf, Wihf_b, G3_ * I_);
  cast_kernel<<<(G3_ * I_ / 4 + 255) / 256, 256, 0, stream>>>(Wihb, Wihb_b, G3_ * I_);
  cast_kernel<<<(SENT_ * 2 * H_ / 4 + 255) / 256, 256, 0, stream>>>(Wsent, Wsent_b, SENT_ * 2 * H_);
  pack_whh<<<(G3_ * H_ + 255) / 256, 256, 0, stream>>>(Whhf, Wpf);
  pack_whh<<<(G3_ * H_ + 255) / 256, 256, 0, stream>>>(Whhb, Wpb);
  tcast_wsim<<<(SENT_ * SENT_ + 255) / 256, 256, 0, stream>>>(Wsim, WsimT_b);
  posseg_kernel<<<1, 64, 0, stream>>>(pos_emb, pos_lin, seg_emb, seg_lin, poslog, segvals);

  mfma_xg<<<dim3(G3_ / 128, (S_ * B_) / 128, 2), 256, 0, stream>>>(x_bf, Wihf_b, bihf, Wihb_b, bihb, xgf_b, xgb_b);

  // persistent GRU scan — regular launch; 256 blocks at 1 block/CU co-resident.
  gru_persistent<<<dim3(256), dim3(256), 0, stream>>>(
      xgf_b, xgb_b, Wpf, Wpb, bhhf, bhhb, h16a, h16b, rnn_b, bar_cnt, bar_sense);

  mfma_nt<1, true><<<dim3(SENT_ / 128, (B_ * S_) / 128), 256, 0, stream>>>(rnn_b, Wsent_b, bsent, sent_b, SENT_, 2 * H_);
  avg_kernel<<<B_, 256, 0, stream>>>(sent_b, ns, avg);
  gemm_nt<2><<<dim3(DOC_ / 64, B_ / 64), 256, 0, stream>>>(avg, Wd1, bd1, d1buf, DOC_, SENT_);
  gemm_nt<0><<<dim3(SENT_ / 64, B_ / 64), 256, 0, stream>>>(d1buf, Wd2, bd2, doc, SENT_, DOC_);
  static_kernel<<<B_ * S_, 64, 0, stream>>>(sent_b, doc, wcont, bcont, ns, poslog, segvals, bias, st);

  mfma_nt<0, false><<<dim3(SENT_ / 128, (B_ * S_) / 128), 256, 0, stream>>>(sent_b, WsimT_b, nullptr, U_b, SENT_, SENT_);

  novelty_all<<<B_, 256, 0, stream>>>(sent_b, U_b, st, out);
}

// Round 7
// 779.827 us; speedup vs baseline: 2.8423x; 2.0440x over previous
//
#include <hip/hip_runtime.h>
#include <hip/hip_bf16.h>
#include <math.h>

#define B_    256
#define S_    50
#define I_    1024
#define H_    512
#define G3_   1536   // 3*H
#define SENT_ 512
#define DOC_  1024

typedef short bf16x8 __attribute__((ext_vector_type(8)));
typedef float f32x4 __attribute__((ext_vector_type(4)));

__device__ __forceinline__ float sigf(float x) { return 1.0f / (1.0f + __expf(-x)); }

// async global->LDS, 16B per lane. LDS dest = wave-uniform base + lane*16.
__device__ __forceinline__ void gload16(const void* g, void* l) {
  __builtin_amdgcn_global_load_lds((const __attribute__((address_space(1))) void*)g,
                                   (__attribute__((address_space(3))) void*)l, 16, 0, 0);
}

// ===========================================================================
// bf16 MFMA GEMM (m97 structure), 128x128 tile, BK=64 — unchanged from R2.
// ===========================================================================
__global__ __launch_bounds__(256) void mfma_xg(
    const __hip_bfloat16* __restrict__ x,
    const __hip_bfloat16* __restrict__ Wf, const float* __restrict__ bf_,
    const __hip_bfloat16* __restrict__ Wb, const float* __restrict__ bb_,
    __hip_bfloat16* __restrict__ xgf, __hip_bfloat16* __restrict__ xgb) {
  __shared__ __align__(16) short As[128 * 64];
  __shared__ __align__(16) short Ws[128 * 64];
  const int dir = blockIdx.z;
  const __hip_bfloat16* W = dir ? Wb : Wf;
  const float* bias = dir ? bb_ : bf_;
  __hip_bfloat16* out = dir ? xgb : xgf;
  const int tid = threadIdx.x;
  const int m0 = blockIdx.y * 128, n0 = blockIdx.x * 128;
  const int s = blockIdx.y >> 1, b_base = (blockIdx.y & 1) * 128;
  const int s_eff = dir ? (S_ - 1 - s) : s;
  const int lane = tid & 63, w = tid >> 6;
  const int moff = (w & 1) * 64, noff = (w >> 1) * 64;
  const int frow = lane & 15, quad = lane >> 4;
  const int rr = tid >> 3, gs = tid & 7;
  f32x4 acc[4][4] = {};
  for (int kc = 0; kc < I_; kc += 64) {
#pragma unroll
    for (int iss = 0; iss < 4; iss++) {
      int r = iss * 32 + rr;
      int col = kc + ((gs ^ (r & 7)) << 3);
      gload16(x + ((size_t)(b_base + r) * S_ + s_eff) * I_ + col, &As[(iss * 256 + w * 64) * 8]);
    }
#pragma unroll
    for (int iss = 0; iss < 4; iss++) {
      int r = iss * 32 + rr;
      int col = kc + ((gs ^ (r & 7)) << 3);
      gload16(W + (size_t)(n0 + r) * I_ + col, &Ws[(iss * 256 + w * 64) * 8]);
    }
    __syncthreads();
#pragma unroll
    for (int ks = 0; ks < 2; ks++) {
      int kg = ks * 4 + quad;
      bf16x8 af[4], bfr[4];
#pragma unroll
      for (int mf = 0; mf < 4; mf++) {
        int r = moff + mf * 16 + frow;
        af[mf] = *(const bf16x8*)&As[(r * 8 + (kg ^ (r & 7))) * 8];
      }
#pragma unroll
      for (int nf = 0; nf < 4; nf++) {
        int r = noff + nf * 16 + frow;
        bfr[nf] = *(const bf16x8*)&Ws[(r * 8 + (kg ^ (r & 7))) * 8];
      }
#pragma unroll
      for (int mf = 0; mf < 4; mf++)
#pragma unroll
        for (int nf = 0; nf < 4; nf++)
          acc[mf][nf] = __builtin_amdgcn_mfma_f32_16x16x32_bf16(af[mf], bfr[nf], acc[mf][nf], 0, 0, 0);
    }
    __syncthreads();
  }
#pragma unroll
  for (int mf = 0; mf < 4; mf++) {
    int rowb = m0 + moff + mf * 16 + quad * 4;
#pragma unroll
    for (int nf = 0; nf < 4; nf++) {
      int col = n0 + noff + nf * 16 + frow;
      float bv = bias[col];
      f32x4 c = acc[mf][nf];
#pragma unroll
      for (int rg = 0; rg < 4; rg++)
        out[(size_t)(rowb + rg) * G3_ + col] = __float2bfloat16(c[rg] + bv);
    }
  }
}

template <int ACT, bool HASBIAS>
__global__ __launch_bounds__(256) void mfma_nt(
    const __hip_bfloat16* __restrict__ A, const __hip_bfloat16* __restrict__ W,
    const float* __restrict__ bias, __hip_bfloat16* __restrict__ outb, int N, int K) {
  __shared__ __align__(16) short As[128 * 64];
  __shared__ __align__(16) short Ws[128 * 64];
  const int tid = threadIdx.x;
  const int m0 = blockIdx.y * 128, n0 = blockIdx.x * 128;
  const int lane = tid & 63, w = tid >> 6;
  const int moff = (w & 1) * 64, noff = (w >> 1) * 64;
  const int frow = lane & 15, quad = lane >> 4;
  const int rr = tid >> 3, gs = tid & 7;
  f32x4 acc[4][4] = {};
  for (int kc = 0; kc < K; kc += 64) {
#pragma unroll
    for (int iss = 0; iss < 4; iss++) {
      int r = iss * 32 + rr;
      int col = kc + ((gs ^ (r & 7)) << 3);
      gload16(A + (size_t)(m0 + r) * K + col, &As[(iss * 256 + w * 64) * 8]);
    }
#pragma unroll
    for (int iss = 0; iss < 4; iss++) {
      int r = iss * 32 + rr;
      int col = kc + ((gs ^ (r & 7)) << 3);
      gload16(W + (size_t)(n0 + r) * K + col, &Ws[(iss * 256 + w * 64) * 8]);
    }
    __syncthreads();
#pragma unroll
    for (int ks = 0; ks < 2; ks++) {
      int kg = ks * 4 + quad;
      bf16x8 af[4], bfr[4];
#pragma unroll
      for (int mf = 0; mf < 4; mf++) {
        int r = moff + mf * 16 + frow;
        af[mf] = *(const bf16x8*)&As[(r * 8 + (kg ^ (r & 7))) * 8];
      }
#pragma unroll
      for (int nf = 0; nf < 4; nf++) {
        int r = noff + nf * 16 + frow;
        bfr[nf] = *(const bf16x8*)&Ws[(r * 8 + (kg ^ (r & 7))) * 8];
      }
#pragma unroll
      for (int mf = 0; mf < 4; mf++)
#pragma unroll
        for (int nf = 0; nf < 4; nf++)
          acc[mf][nf] = __builtin_amdgcn_mfma_f32_16x16x32_bf16(af[mf], bfr[nf], acc[mf][nf], 0, 0, 0);
    }
    __syncthreads();
  }
#pragma unroll
  for (int mf = 0; mf < 4; mf++) {
    int rowb = m0 + moff + mf * 16 + quad * 4;
#pragma unroll
    for (int nf = 0; nf < 4; nf++) {
      int col = n0 + noff + nf * 16 + frow;
      float bv = HASBIAS ? bias[col] : 0.f;
      f32x4 c = acc[mf][nf];
#pragma unroll
      for (int rg = 0; rg < 4; rg++) {
        float v = c[rg] + bv;
        if (ACT == 1) v = fmaxf(v, 0.f);
        outb[(size_t)(rowb + rg) * N + col] = __float2bfloat16(v);
      }
    }
  }
}

// ---------------------------------------------------------------------------
// Persistent GRU scan (regular launch, 256 blocks, 1 block/CU).
// R7 h-exchange: NO cache-wide fences. h stores/loads are agent-scope relaxed
// ATOMICS (write-through / coherent-point reads, sc0 sc1) -> no buffer_wbl2 /
// buffer_inv per step, xg+W stay cached. Barrier: per-block arrival flag
// (own 256B slot); wave0 lanes 0..31 poll the group's 32 flags in parallel
// (one load latency per round, vs R6's serialized 32-RMW chain).
// ---------------------------------------------------------------------------
__global__ __launch_bounds__(256, 1) void gru_persistent(
    const __hip_bfloat16* __restrict__ xgf, const __hip_bfloat16* __restrict__ xgb,
    const __hip_bfloat16* __restrict__ Wpf, const __hip_bfloat16* __restrict__ Wpb,
    const float* __restrict__ bhhf, const float* __restrict__ bhhb,
    __hip_bfloat16* __restrict__ h16a, __hip_bfloat16* __restrict__ h16b,
    __hip_bfloat16* __restrict__ rnn,
    unsigned int* __restrict__ arrive) {
  const int bid = blockIdx.x;
  const int dir = bid >> 7;
  const int bt = (bid >> 5) & 3;
  const int jt = bid & 31;
  const int g8 = bid >> 5;  // dir*4 + bt
  const int tid = threadIdx.x;
  const int w = tid >> 6, lane = tid & 63;
  const int frow = lane & 15, quad = lane >> 4;
  const __hip_bfloat16* xg = dir ? xgb : xgf;
  const __hip_bfloat16* Wp = dir ? Wpb : Wpf;
  const float* bhh = dir ? bhhb : bhhf;

  unsigned int* my_flag = arrive + bid * 64;  // 256B slot per block

  const int j = jt * 16 + frow;
  const int brow0 = bt * 64 + w * 16 + quad * 4;  // first of this lane's 4 b rows
  const float br = bhh[j], bz = bhh[H_ + j], bn = bhh[2 * H_ + j];

  // persistent W_hh fragments: 3 gates x 16 ksteps (192 VGPRs)
  bf16x8 wf[3][16];
#pragma unroll
  for (int g = 0; g < 3; g++)
#pragma unroll
    for (int ks = 0; ks < 16; ks++)
      wf[g][ks] = *(const bf16x8*)(Wp + (size_t)(jt * 48 + g * 16 + frow) * H_ + ks * 32 + quad * 8);

  float hreg[4] = {0.f, 0.f, 0.f, 0.f};
  union U16 { unsigned long long q[2]; bf16x8 v; };

  for (int t = 0; t < S_; t++) {
    const __hip_bfloat16* hp = (t & 1) ? h16b : h16a;
    __hip_bfloat16* hn = (t & 1) ? h16a : h16b;
    // xg(t) for this lane's 4 rows / 3 gates (normal cached loads — never invalidated)
    float xgv[4][3];
#pragma unroll
    for (int rg = 0; rg < 4; rg++) {
      const __hip_bfloat16* xr = xg + ((size_t)t * B_ + brow0 + rg) * G3_;
      xgv[rg][0] = __bfloat162float(xr[j]);
      xgv[rg][1] = __bfloat162float(xr[H_ + j]);
      xgv[rg][2] = __bfloat162float(xr[2 * H_ + j]);
    }
    // A-frags: coherent-point loads (agent relaxed atomics, 8B each)
    const __hip_bfloat16* hprow = hp + (size_t)(dir * B_ + bt * 64 + w * 16 + frow) * H_;
    bf16x8 af[16];
#pragma unroll
    for (int ks = 0; ks < 16; ks++) {
      const unsigned long long* p = (const unsigned long long*)(hprow + ks * 32 + quad * 8);
      U16 u;
      u.q[0] = __hip_atomic_load(p, __ATOMIC_RELAXED, __HIP_MEMORY_SCOPE_AGENT);
      u.q[1] = __hip_atomic_load(p + 1, __ATOMIC_RELAXED, __HIP_MEMORY_SCOPE_AGENT);
      af[ks] = u.v;
    }
    f32x4 acc[3] = {};
#pragma unroll
    for (int ks = 0; ks < 16; ks++)
#pragma unroll
      for (int g = 0; g < 3; g++)
        acc[g] = __builtin_amdgcn_mfma_f32_16x16x32_bf16(af[ks], wf[g][ks], acc[g], 0, 0, 0);

    const int s_orig = dir ? (S_ - 1 - t) : t;
#pragma unroll
    for (int rg = 0; rg < 4; rg++) {
      int b = brow0 + rg;
      float r = sigf(xgv[rg][0] + acc[0][rg] + br);
      float z = sigf(xgv[rg][1] + acc[1][rg] + bz);
      float n = tanhf(xgv[rg][2] + r * (acc[2][rg] + bn));
      float h = (1.f - z) * n + z * hreg[rg];
      hreg[rg] = h;
      __hip_bfloat16 hb = __float2bfloat16(h);
      // write-through atomic store (visible at coherence point, no wbl2 needed)
      unsigned short us;
      __builtin_memcpy(&us, &hb, 2);
      __hip_atomic_store((unsigned short*)(hn + (size_t)(dir * B_ + b) * H_ + j), us,
                         __ATOMIC_RELAXED, __HIP_MEMORY_SCOPE_AGENT);
      rnn[((size_t)b * S_ + s_orig) * (2 * H_) + dir * H_ + j] = hb;
    }

    if (t + 1 < S_) {
      __syncthreads();  // each wave drains vmcnt before s_barrier -> h stores done
      if (tid == 0)
        __hip_atomic_store(my_flag, (unsigned)(t + 1), __ATOMIC_RELAXED,
                           __HIP_MEMORY_SCOPE_AGENT);
      if (w == 0) {
        // lanes 0..31 poll the group's 32 flags in parallel
        unsigned int* fl = arrive + ((size_t)(g8 * 32 + (lane & 31))) * 64;
        for (int spin = 0; spin < (1 << 17); spin++) {
          unsigned v = (lane < 32)
                           ? __hip_atomic_load(fl, __ATOMIC_RELAXED, __HIP_MEMORY_SCOPE_AGENT)
                           : (unsigned)(t + 1);
          if (__ballot(v >= (unsigned)(t + 1)) == ~0ull) break;
          __builtin_amdgcn_s_sleep(1);
        }
      }
      __syncthreads();
    }
  }
}

// ---------------------------------------------------------------------------
// fp32 tiled GEMM (small doc GEMMs)
// ---------------------------------------------------------------------------
template <int ACT>
__global__ __launch_bounds__(256) void gemm_nt(const float* __restrict__ A,
                                               const float* __restrict__ W,
                                               const float* __restrict__ bias,
                                               float* __restrict__ C, int N, int K) {
  __shared__ float As[16][68];
  __shared__ float Bs[16][68];
  const int t = threadIdx.x;
  const int tx = t & 15, ty = t >> 4;
  const int m0 = blockIdx.y * 64, n0 = blockIdx.x * 64;
  const int lr = t >> 2, lc = t & 3;
  const float* Arow = A + (size_t)(m0 + lr) * K;
  const float* Wrow = W + (size_t)(n0 + lr) * K;
  float acc[4][4] = {};
  for (int kc = 0; kc < K; kc += 16) {
    float4 av = *(const float4*)(Arow + kc + lc * 4);
    float4 wv = *(const float4*)(Wrow + kc + lc * 4);
    As[lc * 4 + 0][lr] = av.x; As[lc * 4 + 1][lr] = av.y;
    As[lc * 4 + 2][lr] = av.z; As[lc * 4 + 3][lr] = av.w;
    Bs[lc * 4 + 0][lr] = wv.x; Bs[lc * 4 + 1][lr] = wv.y;
    Bs[lc * 4 + 2][lr] = wv.z; Bs[lc * 4 + 3][lr] = wv.w;
    __syncthreads();
#pragma unroll
    for (int k = 0; k < 16; k++) {
      float4 a4 = *(const float4*)&As[k][ty * 4];
      float4 b4 = *(const float4*)&Bs[k][tx * 4];
      float ar[4] = {a4.x, a4.y, a4.z, a4.w};
      float br[4] = {b4.x, b4.y, b4.z, b4.w};
#pragma unroll
      for (int i = 0; i < 4; i++)
#pragma unroll
        for (int jx = 0; jx < 4; jx++) acc[i][jx] = fmaf(ar[i], br[jx], acc[i][jx]);
    }
    __syncthreads();
  }
  float4 bv = *(const float4*)&bias[n0 + tx * 4];
  float bb[4] = {bv.x, bv.y, bv.z, bv.w};
#pragma unroll
  for (int i = 0; i < 4; i++) {
    float o[4];
#pragma unroll
    for (int jx = 0; jx < 4; jx++) {
      float v = acc[i][jx] + bb[jx];
      if (ACT == 1) v = fmaxf(v, 0.f);
      if (ACT == 2) v = tanhf(v);
      o[jx] = v;
    }
    *(float4*)&C[(size_t)(m0 + ty * 4 + i) * N + n0 + tx * 4] = float4{o[0], o[1], o[2], o[3]};
  }
}

// ------------------------- small helper kernels ----------------------------
__global__ void cast_kernel(const float* __restrict__ in, __hip_bfloat16* __restrict__ out, int n) {
  int i = (blockIdx.x * blockDim.x + threadIdx.x) * 4;
  if (i + 3 < n) {
    float4 v = *(const float4*)(in + i);
    out[i + 0] = __float2bfloat16(v.x);
    out[i + 1] = __float2bfloat16(v.y);
    out[i + 2] = __float2bfloat16(v.z);
    out[i + 3] = __float2bfloat16(v.w);
  }
}

// pack W_hh: row p = (j>>4)*48 + g*16 + (j&15)  (16-j slices, 3 gates each)
__global__ void pack_whh(const float* __restrict__ Whh, __hip_bfloat16* __restrict__ outp) {
  int idx = blockIdx.x * 256 + threadIdx.x;
  if (idx >= G3_ * H_) return;
  int k = idx & 511;
  int row = idx >> 9;  // g*512 + j
  int g = row >> 9, j = row & 511;
  int p = (j >> 4) * 48 + g * 16 + (j & 15);
  outp[(size_t)p * H_ + k] = __float2bfloat16(Whh[idx]);
}

__global__ void tcast_wsim(const float* __restrict__ Wsim, __hip_bfloat16* __restrict__ outT) {
  int idx = blockIdx.x * 256 + threadIdx.x;
  if (idx >= SENT_ * SENT_) return;
  int i = idx >> 9, j = idx & 511;
  outT[(size_t)j * SENT_ + i] = __float2bfloat16(Wsim[idx]);
}

__global__ __launch_bounds__(256) void avg_kernel(const __hip_bfloat16* __restrict__ sent,
                                                  const int* __restrict__ ns,
                                                  float* __restrict__ avg) {
  int b = blockIdx.x, tid = threadIdx.x;
  const __hip_bfloat16* base = sent + (size_t)b * S_ * SENT_;
  float a0 = 0.f, a1 = 0.f;
  for (int s = 0; s < S_; s++) {
    a0 += __bfloat162float(base[s * SENT_ + tid]);
    a1 += __bfloat162float(base[s * SENT_ + 256 + tid]);
  }
  float inv = 1.0f / (float)ns[b];
  avg[(size_t)b * SENT_ + tid] = a0 * inv;
  avg[(size_t)b * SENT_ + 256 + tid] = a1 * inv;
}

__global__ void posseg_kernel(const float* __restrict__ pos_emb, const float* __restrict__ pos_lin,
                              const float* __restrict__ seg_emb, const float* __restrict__ seg_lin,
                              float* __restrict__ pos_logits, float* __restrict__ seg_vals) {
  int tid = threadIdx.x;
  if (tid < S_) {
    int idx = tid + 1; if (idx > 25) idx = 25;
    float a = 0.f;
    for (int k = 0; k < 50; k++) a += pos_emb[idx * 50 + k] * pos_lin[k];
    pos_logits[tid] = a;
  }
  if (tid < 5) {
    float a = 0.f;
    for (int k = 0; k < 50; k++) a += seg_emb[tid * 50 + k] * seg_lin[k];
    seg_vals[tid] = a;
  }
}

__global__ __launch_bounds__(64) void static_kernel(
    const __hip_bfloat16* __restrict__ sent, const float* __restrict__ doc,
    const float* __restrict__ wcont, const float* __restrict__ bcont,
    const int* __restrict__ ns, const float* __restrict__ pos_logits,
    const float* __restrict__ seg_vals, const float* __restrict__ bias,
    float* __restrict__ st) {
  int bs = blockIdx.x;
  int b = bs / S_, s = bs % S_;
  int lane = threadIdx.x;
  const __hip_bfloat16* sr = sent + (size_t)bs * SENT_;
  const float* dr = doc + (size_t)b * SENT_;
  float a0 = 0.f, a1 = 0.f;
#pragma unroll
  for (int ii = 0; ii < 8; ii++) {
    int k = ii * 64 + lane;
    float v = __bfloat162float(sr[k]);
    a0 += v * wcont[k];
    a1 += v * dr[k];
  }
#pragma unroll
  for (int off = 32; off; off >>= 1) {
    a0 += __shfl_down(a0, off);
    a1 += __shfl_down(a1, off);
  }
  if (lane == 0) {
    float chunk = rintf((float)ns[b] * 0.25f);
    float relf = ceilf((float)(s + 1) / chunk);
    relf = fminf(fmaxf(relf, 0.f), 4.f);
    int rel = (int)relf;
    st[s * B_ + b] = a0 + bcont[0] + a1 + pos_logits[s] + seg_vals[rel] + bias[0];
  }
}

__global__ __launch_bounds__(256) void novelty_all(
    const __hip_bfloat16* __restrict__ sent, const __hip_bfloat16* __restrict__ U,
    const float* __restrict__ st, float* __restrict__ out) {
  __shared__ float wred[4];
  int b = blockIdx.x, tid = threadIdx.x;
  float s0 = 0.f, s1 = 0.f;
  for (int t = 0; t < S_; t++) {
    const __hip_bfloat16* ur = U + ((size_t)b * S_ + t) * SENT_;
    float p = __bfloat162float(ur[tid]) * tanhf(s0) +
              __bfloat162float(ur[tid + 256]) * tanhf(s1);
#pragma unroll
    for (int off = 32; off; off >>= 1) p += __shfl_down(p, off);
    if ((tid & 63) == 0) wred[tid >> 6] = p;
    __syncthreads();
    float sim = wred[0] + wred[1] + wred[2] + wred[3];
    float logit = st[t * B_ + b] - sim;
    if (tid == 0) out[(size_t)t * B_ + b] = logit;
    float sg = sigf(logit);
    const __hip_bfloat16* sr = sent + ((size_t)b * S_ + t) * SENT_;
    s0 += __bfloat162float(sr[tid]) * sg;
    s1 += __bfloat162float(sr[tid + 256]) * sg;
    __syncthreads();
  }
}

extern "C" void kernel_launch(void* const* d_in, const int* in_sizes, int n_in,
                              void* d_out, int out_size, void* d_ws, size_t ws_size,
                              hipStream_t stream) {
  const float* x = (const float*)d_in[0];
  const int* ns = (const int*)d_in[1];
  const float* Wihf = (const float*)d_in[2];
  const float* Whhf = (const float*)d_in[3];
  const float* bihf = (const float*)d_in[4];
  const float* bhhf = (const float*)d_in[5];
  const float* Wihb = (const float*)d_in[6];
  const float* Whhb = (const float*)d_in[7];
  const float* bihb = (const float*)d_in[8];
  const float* bhhb = (const float*)d_in[9];
  const float* Wsent = (const float*)d_in[10];
  const float* bsent = (const float*)d_in[11];
  const float* wcont = (const float*)d_in[12];
  const float* bcont = (const float*)d_in[13];
  const float* Wd1 = (const float*)d_in[14];
  const float* bd1 = (const float*)d_in[15];
  const float* Wd2 = (const float*)d_in[16];
  const float* bd2 = (const float*)d_in[17];
  const float* Wsim = (const float*)d_in[18];
  const float* bias = (const float*)d_in[19];
  const float* pos_emb = (const float*)d_in[20];
  const float* pos_lin = (const float*)d_in[21];
  const float* seg_emb = (const float*)d_in[22];
  const float* seg_lin = (const float*)d_in[23];
  float* out = (float*)d_out;

  char* base = (char*)d_ws;
  size_t off = 0;
  auto alloc = [&](size_t bytes) { char* p = base + off; off += (bytes + 255) & ~255ull; return p; };
  __hip_bfloat16* xgf_b  = (__hip_bfloat16*)alloc((size_t)S_ * B_ * G3_ * 2);
  __hip_bfloat16* xgb_b  = (__hip_bfloat16*)alloc((size_t)S_ * B_ * G3_ * 2);
  char* region1          = alloc((size_t)B_ * S_ * I_ * 2);  // x_bf, later sent_b+U_b
  __hip_bfloat16* x_bf   = (__hip_bfloat16*)region1;
  __hip_bfloat16* sent_b = (__hip_bfloat16*)region1;
  __hip_bfloat16* U_b    = (__hip_bfloat16*)(region1 + (size_t)B_ * S_ * SENT_ * 2);
  __hip_bfloat16* rnn_b  = (__hip_bfloat16*)alloc((size_t)B_ * S_ * 2 * H_ * 2);
  __hip_bfloat16* Wihf_b = (__hip_bfloat16*)alloc((size_t)G3_ * I_ * 2);
  __hip_bfloat16* Wihb_b = (__hip_bfloat16*)alloc((size_t)G3_ * I_ * 2);
  __hip_bfloat16* Wpf    = (__hip_bfloat16*)alloc((size_t)G3_ * H_ * 2);
  __hip_bfloat16* Wpb    = (__hip_bfloat16*)alloc((size_t)G3_ * H_ * 2);
  __hip_bfloat16* Wsent_b= (__hip_bfloat16*)alloc((size_t)SENT_ * 2 * H_ * 2);
  __hip_bfloat16* WsimT_b= (__hip_bfloat16*)alloc((size_t)SENT_ * SENT_ * 2);
  __hip_bfloat16* h16a   = (__hip_bfloat16*)alloc(2 * (size_t)B_ * H_ * 2);  // [dir][B][H]
  __hip_bfloat16* h16b   = (__hip_bfloat16*)alloc(2 * (size_t)B_ * H_ * 2);
  unsigned int* arrive   = (unsigned int*)alloc(256 * 64 * 4);  // 256B slot per block
  float* avg             = (float*)alloc((size_t)B_ * SENT_ * 4);
  float* d1buf           = (float*)alloc((size_t)B_ * DOC_ * 4);
  float* doc             = (float*)alloc((size_t)B_ * SENT_ * 4);
  float* st              = (float*)alloc((size_t)S_ * B_ * 4);
  float* poslog          = (float*)alloc(256);
  float* segvals         = (float*)alloc(64);
  (void)ws_size;

  // zero h16a (t=0 state) and arrival flags
  (void)hipMemsetAsync(h16a, 0, 2 * (size_t)B_ * H_ * 2, stream);
  (void)hipMemsetAsync(arrive, 0, 256 * 64 * 4, stream);

  cast_kernel<<<(B_ * S_ * I_ / 4 + 255) / 256, 256, 0, stream>>>(x, x_bf, B_ * S_ * I_);
  cast_kernel<<<(G3_ * I_ / 4 + 255) / 256, 256, 0, stream>>>(Wihf, Wihf_b, G3_ * I_);
  cast_kernel<<<(G3_ * I_ / 4 + 255) / 256, 256, 0, stream>>>(Wihb, Wihb_b, G3_ * I_);
  cast_kernel<<<(SENT_ * 2 * H_ / 4 + 255) / 256, 256, 0, stream>>>(Wsent, Wsent_b, SENT_ * 2 * H_);
  pack_whh<<<(G3_ * H_ + 255) / 256, 256, 0, stream>>>(Whhf, Wpf);
  pack_whh<<<(G3_ * H_ + 255) / 256, 256, 0, stream>>>(Whhb, Wpb);
  tcast_wsim<<<(SENT_ * SENT_ + 255) / 256, 256, 0, stream>>>(Wsim, WsimT_b);
  posseg_kernel<<<1, 64, 0, stream>>>(pos_emb, pos_lin, seg_emb, seg_lin, poslog, segvals);

  mfma_xg<<<dim3(G3_ / 128, (S_ * B_) / 128, 2), 256, 0, stream>>>(x_bf, Wihf_b, bihf, Wihb_b, bihb, xgf_b, xgb_b);

  // persistent GRU scan — regular launch; 256 blocks at 1 block/CU co-resident.
  gru_persistent<<<dim3(256), dim3(256), 0, stream>>>(
      xgf_b, xgb_b, Wpf, Wpb, bhhf, bhhb, h16a, h16b, rnn_b, arrive);

  mfma_nt<1, true><<<dim3(SENT_ / 128, (B_ * S_) / 128), 256, 0, stream>>>(rnn_b, Wsent_b, bsent, sent_b, SENT_, 2 * H_);
  avg_kernel<<<B_, 256, 0, stream>>>(sent_b, ns, avg);
  gemm_nt<2><<<dim3(DOC_ / 64, B_ / 64), 256, 0, stream>>>(avg, Wd1, bd1, d1buf, DOC_, SENT_);
  gemm_nt<0><<<dim3(SENT_ / 64, B_ / 64), 256, 0, stream>>>(d1buf, Wd2, bd2, doc, SENT_, DOC_);
  static_kernel<<<B_ * S_, 64, 0, stream>>>(sent_b, doc, wcont, bcont, ns, poslog, segvals, bias, st);

  mfma_nt<0, false><<<dim3(SENT_ / 128, (B_ * S_) / 128), 256, 0, stream>>>(sent_b, WsimT_b, nullptr, U_b, SENT_, SENT_);

  novelty_all<<<B_, 256, 0, stream>>>(sent_b, U_b, st, out);
}

// Round 8
// 695.480 us; speedup vs baseline: 3.1870x; 1.1213x over previous
//
#include <hip/hip_runtime.h>
#include <hip/hip_bf16.h>
#include <math.h>

#define B_    256
#define S_    50
#define I_    1024
#define H_    512
#define G3_   1536   // 3*H
#define SENT_ 512
#define DOC_  1024

typedef short bf16x8 __attribute__((ext_vector_type(8)));
typedef float f32x4 __attribute__((ext_vector_type(4)));

__device__ __forceinline__ float sigf(float x) { return 1.0f / (1.0f + __expf(-x)); }

// async global->LDS, 16B per lane. LDS dest = wave-uniform base + lane*16.
__device__ __forceinline__ void gload16(const void* g, void* l) {
  __builtin_amdgcn_global_load_lds((const __attribute__((address_space(1))) void*)g,
                                   (__attribute__((address_space(3))) void*)l, 16, 0, 0);
}

// ===========================================================================
// bf16 MFMA GEMM (m97 structure), 128x128 tile, BK=64 — unchanged from R2.
// ===========================================================================
__global__ __launch_bounds__(256) void mfma_xg(
    const __hip_bfloat16* __restrict__ x,
    const __hip_bfloat16* __restrict__ Wf, const float* __restrict__ bf_,
    const __hip_bfloat16* __restrict__ Wb, const float* __restrict__ bb_,
    __hip_bfloat16* __restrict__ xgf, __hip_bfloat16* __restrict__ xgb) {
  __shared__ __align__(16) short As[128 * 64];
  __shared__ __align__(16) short Ws[128 * 64];
  const int dir = blockIdx.z;
  const __hip_bfloat16* W = dir ? Wb : Wf;
  const float* bias = dir ? bb_ : bf_;
  __hip_bfloat16* out = dir ? xgb : xgf;
  const int tid = threadIdx.x;
  const int m0 = blockIdx.y * 128, n0 = blockIdx.x * 128;
  const int s = blockIdx.y >> 1, b_base = (blockIdx.y & 1) * 128;
  const int s_eff = dir ? (S_ - 1 - s) : s;
  const int lane = tid & 63, w = tid >> 6;
  const int moff = (w & 1) * 64, noff = (w >> 1) * 64;
  const int frow = lane & 15, quad = lane >> 4;
  const int rr = tid >> 3, gs = tid & 7;
  f32x4 acc[4][4] = {};
  for (int kc = 0; kc < I_; kc += 64) {
#pragma unroll
    for (int iss = 0; iss < 4; iss++) {
      int r = iss * 32 + rr;
      int col = kc + ((gs ^ (r & 7)) << 3);
      gload16(x + ((size_t)(b_base + r) * S_ + s_eff) * I_ + col, &As[(iss * 256 + w * 64) * 8]);
    }
#pragma unroll
    for (int iss = 0; iss < 4; iss++) {
      int r = iss * 32 + rr;
      int col = kc + ((gs ^ (r & 7)) << 3);
      gload16(W + (size_t)(n0 + r) * I_ + col, &Ws[(iss * 256 + w * 64) * 8]);
    }
    __syncthreads();
#pragma unroll
    for (int ks = 0; ks < 2; ks++) {
      int kg = ks * 4 + quad;
      bf16x8 af[4], bfr[4];
#pragma unroll
      for (int mf = 0; mf < 4; mf++) {
        int r = moff + mf * 16 + frow;
        af[mf] = *(const bf16x8*)&As[(r * 8 + (kg ^ (r & 7))) * 8];
      }
#pragma unroll
      for (int nf = 0; nf < 4; nf++) {
        int r = noff + nf * 16 + frow;
        bfr[nf] = *(const bf16x8*)&Ws[(r * 8 + (kg ^ (r & 7))) * 8];
      }
#pragma unroll
      for (int mf = 0; mf < 4; mf++)
#pragma unroll
        for (int nf = 0; nf < 4; nf++)
          acc[mf][nf] = __builtin_amdgcn_mfma_f32_16x16x32_bf16(af[mf], bfr[nf], acc[mf][nf], 0, 0, 0);
    }
    __syncthreads();
  }
#pragma unroll
  for (int mf = 0; mf < 4; mf++) {
    int rowb = m0 + moff + mf * 16 + quad * 4;
#pragma unroll
    for (int nf = 0; nf < 4; nf++) {
      int col = n0 + noff + nf * 16 + frow;
      float bv = bias[col];
      f32x4 c = acc[mf][nf];
#pragma unroll
      for (int rg = 0; rg < 4; rg++)
        out[(size_t)(rowb + rg) * G3_ + col] = __float2bfloat16(c[rg] + bv);
    }
  }
}

template <int ACT, bool HASBIAS>
__global__ __launch_bounds__(256) void mfma_nt(
    const __hip_bfloat16* __restrict__ A, const __hip_bfloat16* __restrict__ W,
    const float* __restrict__ bias, __hip_bfloat16* __restrict__ outb, int N, int K) {
  __shared__ __align__(16) short As[128 * 64];
  __shared__ __align__(16) short Ws[128 * 64];
  const int tid = threadIdx.x;
  const int m0 = blockIdx.y * 128, n0 = blockIdx.x * 128;
  const int lane = tid & 63, w = tid >> 6;
  const int moff = (w & 1) * 64, noff = (w >> 1) * 64;
  const int frow = lane & 15, quad = lane >> 4;
  const int rr = tid >> 3, gs = tid & 7;
  f32x4 acc[4][4] = {};
  for (int kc = 0; kc < K; kc += 64) {
#pragma unroll
    for (int iss = 0; iss < 4; iss++) {
      int r = iss * 32 + rr;
      int col = kc + ((gs ^ (r & 7)) << 3);
      gload16(A + (size_t)(m0 + r) * K + col, &As[(iss * 256 + w * 64) * 8]);
    }
#pragma unroll
    for (int iss = 0; iss < 4; iss++) {
      int r = iss * 32 + rr;
      int col = kc + ((gs ^ (r & 7)) << 3);
      gload16(W + (size_t)(n0 + r) * K + col, &Ws[(iss * 256 + w * 64) * 8]);
    }
    __syncthreads();
#pragma unroll
    for (int ks = 0; ks < 2; ks++) {
      int kg = ks * 4 + quad;
      bf16x8 af[4], bfr[4];
#pragma unroll
      for (int mf = 0; mf < 4; mf++) {
        int r = moff + mf * 16 + frow;
        af[mf] = *(const bf16x8*)&As[(r * 8 + (kg ^ (r & 7))) * 8];
      }
#pragma unroll
      for (int nf = 0; nf < 4; nf++) {
        int r = noff + nf * 16 + frow;
        bfr[nf] = *(const bf16x8*)&Ws[(r * 8 + (kg ^ (r & 7))) * 8];
      }
#pragma unroll
      for (int mf = 0; mf < 4; mf++)
#pragma unroll
        for (int nf = 0; nf < 4; nf++)
          acc[mf][nf] = __builtin_amdgcn_mfma_f32_16x16x32_bf16(af[mf], bfr[nf], acc[mf][nf], 0, 0, 0);
    }
    __syncthreads();
  }
#pragma unroll
  for (int mf = 0; mf < 4; mf++) {
    int rowb = m0 + moff + mf * 16 + quad * 4;
#pragma unroll
    for (int nf = 0; nf < 4; nf++) {
      int col = n0 + noff + nf * 16 + frow;
      float bv = HASBIAS ? bias[col] : 0.f;
      f32x4 c = acc[mf][nf];
#pragma unroll
      for (int rg = 0; rg < 4; rg++) {
        float v = c[rg] + bv;
        if (ACT == 1) v = fmaxf(v, 0.f);
        outb[(size_t)(rowb + rg) * N + col] = __float2bfloat16(v);
      }
    }
  }
}

// ---------------------------------------------------------------------------
// Persistent GRU scan v3. Grid 256 = 2 dir x 8 bt(32 rows) x 16 jt(32 cols);
// barrier group = 16 blocks (gi = dir*8+bt). h(t) tile (32x512, 32KB) staged
// cooperatively into LDS via coherent 8B loads (halves inter-wave redundancy;
// group redundancy 32x -> 16x => coherent h traffic 16 -> 8 MB/step).
// Waves 2x2: w&1 = m-half (16 rows), w>>1 = n-half (48 = 3 gates x 16 j).
// Same relaxed-atomic h exchange + per-block arrival flags as R7 (proven).
// ---------------------------------------------------------------------------
__global__ __launch_bounds__(256, 1) void gru_persistent(
    const __hip_bfloat16* __restrict__ xgf, const __hip_bfloat16* __restrict__ xgb,
    const __hip_bfloat16* __restrict__ Wpf, const __hip_bfloat16* __restrict__ Wpb,
    const float* __restrict__ bhhf, const float* __restrict__ bhhb,
    __hip_bfloat16* __restrict__ h16a, __hip_bfloat16* __restrict__ h16b,
    __hip_bfloat16* __restrict__ rnn,
    unsigned int* __restrict__ arrive) {
  __shared__ __align__(16) short Hs[32 * 512];  // 32 KB, XOR-swizzled
  const int bid = blockIdx.x;
  const int dir = bid >> 7;
  const int bt = (bid >> 4) & 7;
  const int jt = bid & 15;
  const int gi = bid >> 4;  // dir*8 + bt, 16 groups of 16 blocks
  const int tid = threadIdx.x;
  const int w = tid >> 6, lane = tid & 63;
  const int frow = lane & 15, quad = lane >> 4;
  const int wm = w & 1, wn = w >> 1;
  const __hip_bfloat16* xg = dir ? xgb : xgf;
  const __hip_bfloat16* Wp = dir ? Wpb : Wpf;
  const float* bhh = dir ? bhhb : bhhf;

  unsigned int* my_flag = arrive + (size_t)bid * 64;  // 256B slot per block

  const int j = jt * 32 + wn * 16 + frow;
  const int brow0 = bt * 32 + wm * 16 + quad * 4;  // lane's first b row
  const int ar = wm * 16 + frow;                   // A-frag row within LDS tile
  const float br = bhh[j], bz = bhh[H_ + j], bn = bhh[2 * H_ + j];

  // W_hh fragments: 3 gates x 16 ksteps; packed row p = (j>>4)*48 + g*16 + (j&15)
  bf16x8 wf[3][16];
#pragma unroll
  for (int g = 0; g < 3; g++)
#pragma unroll
    for (int ks = 0; ks < 16; ks++)
      wf[g][ks] = *(const bf16x8*)(Wp + (size_t)((jt * 2 + wn) * 48 + g * 16 + frow) * H_ +
                                   ks * 32 + quad * 8);

  float hreg[4] = {0.f, 0.f, 0.f, 0.f};
  union U16 { unsigned long long q[2]; bf16x8 v; };

  for (int t = 0; t < S_; t++) {
    const __hip_bfloat16* hp = (t & 1) ? h16b : h16a;
    __hip_bfloat16* hn = (t & 1) ? h16a : h16b;
    // xg(t) (normal cached loads — streamed once, never invalidated)
    float xgv[4][3];
#pragma unroll
    for (int rg = 0; rg < 4; rg++) {
      const __hip_bfloat16* xr = xg + ((size_t)t * B_ + brow0 + rg) * G3_;
      xgv[rg][0] = __bfloat162float(xr[j]);
      xgv[rg][1] = __bfloat162float(xr[H_ + j]);
      xgv[rg][2] = __bfloat162float(xr[2 * H_ + j]);
    }
    // cooperative coherent stage of h(t) tile (32 rows x 512) into swizzled LDS
    const __hip_bfloat16* hbase = hp + (size_t)(dir * B_ + bt * 32) * H_;
#pragma unroll
    for (int i = 0; i < 8; i++) {
      int c = i * 256 + tid;  // 2048 chunks of 8 bf16
      int r = c >> 6, kg = c & 63;
      const unsigned long long* p = (const unsigned long long*)(hbase + (size_t)r * H_ + kg * 8);
      U16 u;
      u.q[0] = __hip_atomic_load(p, __ATOMIC_RELAXED, __HIP_MEMORY_SCOPE_AGENT);
      u.q[1] = __hip_atomic_load(p + 1, __ATOMIC_RELAXED, __HIP_MEMORY_SCOPE_AGENT);
      int q = r * 64 + (kg & 56) + ((kg & 7) ^ (r & 7));
      *(bf16x8*)&Hs[q * 8] = u.v;
    }
    __syncthreads();
    bf16x8 af[16];
#pragma unroll
    for (int ks = 0; ks < 16; ks++) {
      int g2 = ks * 4 + quad;
      int q = ar * 64 + (g2 & 56) + ((g2 & 7) ^ (ar & 7));
      af[ks] = *(const bf16x8*)&Hs[q * 8];
    }
    f32x4 acc[3] = {};
#pragma unroll
    for (int ks = 0; ks < 16; ks++)
#pragma unroll
      for (int g = 0; g < 3; g++)
        acc[g] = __builtin_amdgcn_mfma_f32_16x16x32_bf16(af[ks], wf[g][ks], acc[g], 0, 0, 0);

    const int s_orig = dir ? (S_ - 1 - t) : t;
#pragma unroll
    for (int rg = 0; rg < 4; rg++) {
      int b = brow0 + rg;
      float r = sigf(xgv[rg][0] + acc[0][rg] + br);
      float z = sigf(xgv[rg][1] + acc[1][rg] + bz);
      float n = tanhf(xgv[rg][2] + r * (acc[2][rg] + bn));
      float h = (1.f - z) * n + z * hreg[rg];
      hreg[rg] = h;
      __hip_bfloat16 hb = __float2bfloat16(h);
      unsigned short us;
      __builtin_memcpy(&us, &hb, 2);
      __hip_atomic_store((unsigned short*)(hn + (size_t)(dir * B_ + b) * H_ + j), us,
                         __ATOMIC_RELAXED, __HIP_MEMORY_SCOPE_AGENT);
      rnn[((size_t)b * S_ + s_orig) * (2 * H_) + dir * H_ + j] = hb;
    }

    if (t + 1 < S_) {
      __syncthreads();  // drains vmcnt (h stores at coherence point) + Hs reuse
      if (tid == 0)
        __hip_atomic_store(my_flag, (unsigned)(t + 1), __ATOMIC_RELAXED,
                           __HIP_MEMORY_SCOPE_AGENT);
      if (w == 0) {
        unsigned int* fl = arrive + (size_t)(gi * 16 + (lane & 15)) * 64;
        for (int spin = 0; spin < (1 << 17); spin++) {
          unsigned v = (lane < 16)
                           ? __hip_atomic_load(fl, __ATOMIC_RELAXED, __HIP_MEMORY_SCOPE_AGENT)
                           : (unsigned)(t + 1);
          if (__ballot(v >= (unsigned)(t + 1)) == ~0ull) break;
          __builtin_amdgcn_s_sleep(1);
        }
      }
      __syncthreads();
    }
  }
}

// ---------------------------------------------------------------------------
// fp32 tiled GEMM (small doc GEMMs)
// ---------------------------------------------------------------------------
template <int ACT>
__global__ __launch_bounds__(256) void gemm_nt(const float* __restrict__ A,
                                               const float* __restrict__ W,
                                               const float* __restrict__ bias,
                                               float* __restrict__ C, int N, int K) {
  __shared__ float As[16][68];
  __shared__ float Bs[16][68];
  const int t = threadIdx.x;
  const int tx = t & 15, ty = t >> 4;
  const int m0 = blockIdx.y * 64, n0 = blockIdx.x * 64;
  const int lr = t >> 2, lc = t & 3;
  const float* Arow = A + (size_t)(m0 + lr) * K;
  const float* Wrow = W + (size_t)(n0 + lr) * K;
  float acc[4][4] = {};
  for (int kc = 0; kc < K; kc += 16) {
    float4 av = *(const float4*)(Arow + kc + lc * 4);
    float4 wv = *(const float4*)(Wrow + kc + lc * 4);
    As[lc * 4 + 0][lr] = av.x; As[lc * 4 + 1][lr] = av.y;
    As[lc * 4 + 2][lr] = av.z; As[lc * 4 + 3][lr] = av.w;
    Bs[lc * 4 + 0][lr] = wv.x; Bs[lc * 4 + 1][lr] = wv.y;
    Bs[lc * 4 + 2][lr] = wv.z; Bs[lc * 4 + 3][lr] = wv.w;
    __syncthreads();
#pragma unroll
    for (int k = 0; k < 16; k++) {
      float4 a4 = *(const float4*)&As[k][ty * 4];
      float4 b4 = *(const float4*)&Bs[k][tx * 4];
      float ar[4] = {a4.x, a4.y, a4.z, a4.w};
      float br[4] = {b4.x, b4.y, b4.z, b4.w};
#pragma unroll
      for (int i = 0; i < 4; i++)
#pragma unroll
        for (int jx = 0; jx < 4; jx++) acc[i][jx] = fmaf(ar[i], br[jx], acc[i][jx]);
    }
    __syncthreads();
  }
  float4 bv = *(const float4*)&bias[n0 + tx * 4];
  float bb[4] = {bv.x, bv.y, bv.z, bv.w};
#pragma unroll
  for (int i = 0; i < 4; i++) {
    float o[4];
#pragma unroll
    for (int jx = 0; jx < 4; jx++) {
      float v = acc[i][jx] + bb[jx];
      if (ACT == 1) v = fmaxf(v, 0.f);
      if (ACT == 2) v = tanhf(v);
      o[jx] = v;
    }
    *(float4*)&C[(size_t)(m0 + ty * 4 + i) * N + n0 + tx * 4] = float4{o[0], o[1], o[2], o[3]};
  }
}

// ------------------------- fused prep kernel -------------------------------
// One launch replaces: 3 weight casts, 2 W_hh packs, Wsim transpose-cast,
// h16a zero, arrive zero, posseg. Segments by blockIdx.x range.
#define PREP_CAST1   1536   // Wihf  (1536*1024 elems, 1024/block)
#define PREP_CAST2   3072   // Wihb
#define PREP_CAST3   3584   // Wsent (512*1024)
#define PREP_PACK1   4352   // Whhf pack (786432 elems, 1024/block)
#define PREP_PACK2   5120   // Whhb pack
#define PREP_TSIM    6144   // Wsim transpose (262144, 256/block)
#define PREP_ZH      6272   // h16a zero (262144 shorts, 2048/block)
#define PREP_ZF      6288   // arrive zero (16384 u32, 1024/block)
#define PREP_POS     6289   // posseg
__global__ __launch_bounds__(256) void prep_all(
    const float* __restrict__ Wihf, const float* __restrict__ Wihb,
    const float* __restrict__ Wsent, const float* __restrict__ Whhf,
    const float* __restrict__ Whhb, const float* __restrict__ Wsim,
    const float* __restrict__ pos_emb, const float* __restrict__ pos_lin,
    const float* __restrict__ seg_emb, const float* __restrict__ seg_lin,
    __hip_bfloat16* __restrict__ Wihf_b, __hip_bfloat16* __restrict__ Wihb_b,
    __hip_bfloat16* __restrict__ Wsent_b, __hip_bfloat16* __restrict__ Wpf,
    __hip_bfloat16* __restrict__ Wpb, __hip_bfloat16* __restrict__ WsimT_b,
    __hip_bfloat16* __restrict__ h16a, unsigned int* __restrict__ arrive,
    float* __restrict__ pos_logits, float* __restrict__ seg_vals) {
  const int blk = blockIdx.x, tid = threadIdx.x;
  if (blk < PREP_CAST2) {  // Wih casts
    const float* src = (blk < PREP_CAST1) ? Wihf : Wihb;
    __hip_bfloat16* dst = (blk < PREP_CAST1) ? Wihf_b : Wihb_b;
    int lb = (blk < PREP_CAST1) ? blk : blk - PREP_CAST1;
    int i = lb * 1024 + tid * 4;
    float4 v = *(const float4*)(src + i);
    dst[i] = __float2bfloat16(v.x); dst[i + 1] = __float2bfloat16(v.y);
    dst[i + 2] = __float2bfloat16(v.z); dst[i + 3] = __float2bfloat16(v.w);
  } else if (blk < PREP_CAST3) {
    int i = (blk - PREP_CAST2) * 1024 + tid * 4;
    float4 v = *(const float4*)(Wsent + i);
    Wsent_b[i] = __float2bfloat16(v.x); Wsent_b[i + 1] = __float2bfloat16(v.y);
    Wsent_b[i + 2] = __float2bfloat16(v.z); Wsent_b[i + 3] = __float2bfloat16(v.w);
  } else if (blk < PREP_PACK2) {  // W_hh packs: p = (j>>4)*48 + g*16 + (j&15)
    const float* src = (blk < PREP_PACK1) ? Whhf : Whhb;
    __hip_bfloat16* dst = (blk < PREP_PACK1) ? Wpf : Wpb;
    int lb = (blk < PREP_PACK1) ? blk - PREP_CAST3 : blk - PREP_PACK1;
    int e = lb * 1024 + tid * 4;  // 4 consecutive k within one row
    int row = e >> 9, k = e & 511;  // row = g*512 + j
    int g = row >> 9, j = row & 511;
    int p = (j >> 4) * 48 + g * 16 + (j & 15);
    float4 v = *(const float4*)(src + (size_t)row * 512 + k);
    __hip_bfloat16* d = dst + (size_t)p * 512 + k;
    d[0] = __float2bfloat16(v.x); d[1] = __float2bfloat16(v.y);
    d[2] = __float2bfloat16(v.z); d[3] = __float2bfloat16(v.w);
  } else if (blk < PREP_TSIM) {
    int idx = (blk - PREP_PACK2) * 256 + tid;
    int i = idx >> 9, j = idx & 511;
    WsimT_b[(size_t)j * 512 + i] = __float2bfloat16(Wsim[idx]);
  } else if (blk < PREP_ZH) {
    int i = (blk - PREP_TSIM) * 2048 + tid * 8;
    float4 z = {0.f, 0.f, 0.f, 0.f};
    *(float4*)((short*)h16a + i) = z;  // 8 bf16 zeros
  } else if (blk < PREP_ZF) {
    int i = (blk - PREP_ZH) * 1024 + tid * 4;
    float4 z = {0.f, 0.f, 0.f, 0.f};
    *(float4*)(arrive + i) = z;
  } else {  // posseg
    if (tid < S_) {
      int idx = tid + 1; if (idx > 25) idx = 25;
      float a = 0.f;
      for (int k = 0; k < 50; k++) a += pos_emb[idx * 50 + k] * pos_lin[k];
      pos_logits[tid] = a;
    }
    if (tid < 5) {
      float a = 0.f;
      for (int k = 0; k < 50; k++) a += seg_emb[tid * 50 + k] * seg_lin[k];
      seg_vals[tid] = a;
    }
  }
}

__global__ void cast_kernel(const float* __restrict__ in, __hip_bfloat16* __restrict__ out, int n) {
  int i = (blockIdx.x * blockDim.x + threadIdx.x) * 4;
  if (i + 3 < n) {
    float4 v = *(const float4*)(in + i);
    out[i + 0] = __float2bfloat16(v.x);
    out[i + 1] = __float2bfloat16(v.y);
    out[i + 2] = __float2bfloat16(v.z);
    out[i + 3] = __float2bfloat16(v.w);
  }
}

__global__ __launch_bounds__(256) void avg_kernel(const __hip_bfloat16* __restrict__ sent,
                                                  const int* __restrict__ ns,
                                                  float* __restrict__ avg) {
  int b = blockIdx.x, tid = threadIdx.x;
  const __hip_bfloat16* base = sent + (size_t)b * S_ * SENT_;
  float a0 = 0.f, a1 = 0.f;
  for (int s = 0; s < S_; s++) {
    a0 += __bfloat162float(base[s * SENT_ + tid]);
    a1 += __bfloat162float(base[s * SENT_ + 256 + tid]);
  }
  float inv = 1.0f / (float)ns[b];
  avg[(size_t)b * SENT_ + tid] = a0 * inv;
  avg[(size_t)b * SENT_ + 256 + tid] = a1 * inv;
}

__global__ __launch_bounds__(64) void static_kernel(
    const __hip_bfloat16* __restrict__ sent, const float* __restrict__ doc,
    const float* __restrict__ wcont, const float* __restrict__ bcont,
    const int* __restrict__ ns, const float* __restrict__ pos_logits,
    const float* __restrict__ seg_vals, const float* __restrict__ bias,
    float* __restrict__ st) {
  int bs = blockIdx.x;
  int b = bs / S_, s = bs % S_;
  int lane = threadIdx.x;
  const __hip_bfloat16* sr = sent + (size_t)bs * SENT_;
  const float* dr = doc + (size_t)b * SENT_;
  float a0 = 0.f, a1 = 0.f;
#pragma unroll
  for (int ii = 0; ii < 8; ii++) {
    int k = ii * 64 + lane;
    float v = __bfloat162float(sr[k]);
    a0 += v * wcont[k];
    a1 += v * dr[k];
  }
#pragma unroll
  for (int off = 32; off; off >>= 1) {
    a0 += __shfl_down(a0, off);
    a1 += __shfl_down(a1, off);
  }
  if (lane == 0) {
    float chunk = rintf((float)ns[b] * 0.25f);
    float relf = ceilf((float)(s + 1) / chunk);
    relf = fminf(fmaxf(relf, 0.f), 4.f);
    int rel = (int)relf;
    st[s * B_ + b] = a0 + bcont[0] + a1 + pos_logits[s] + seg_vals[rel] + bias[0];
  }
}

__global__ __launch_bounds__(256) void novelty_all(
    const __hip_bfloat16* __restrict__ sent, const __hip_bfloat16* __restrict__ U,
    const float* __restrict__ st, float* __restrict__ out) {
  __shared__ float wred[4];
  int b = blockIdx.x, tid = threadIdx.x;
  float s0 = 0.f, s1 = 0.f;
  for (int t = 0; t < S_; t++) {
    const __hip_bfloat16* ur = U + ((size_t)b * S_ + t) * SENT_;
    float p = __bfloat162float(ur[tid]) * tanhf(s0) +
              __bfloat162float(ur[tid + 256]) * tanhf(s1);
#pragma unroll
    for (int off = 32; off; off >>= 1) p += __shfl_down(p, off);
    if ((tid & 63) == 0) wred[tid >> 6] = p;
    __syncthreads();
    float sim = wred[0] + wred[1] + wred[2] + wred[3];
    float logit = st[t * B_ + b] - sim;
    if (tid == 0) out[(size_t)t * B_ + b] = logit;
    float sg = sigf(logit);
    const __hip_bfloat16* sr = sent + ((size_t)b * S_ + t) * SENT_;
    s0 += __bfloat162float(sr[tid]) * sg;
    s1 += __bfloat162float(sr[tid + 256]) * sg;
    __syncthreads();
  }
}

extern "C" void kernel_launch(void* const* d_in, const int* in_sizes, int n_in,
                              void* d_out, int out_size, void* d_ws, size_t ws_size,
                              hipStream_t stream) {
  const float* x = (const float*)d_in[0];
  const int* ns = (const int*)d_in[1];
  const float* Wihf = (const float*)d_in[2];
  const float* Whhf = (const float*)d_in[3];
  const float* bihf = (const float*)d_in[4];
  const float* bhhf = (const float*)d_in[5];
  const float* Wihb = (const float*)d_in[6];
  const float* Whhb = (const float*)d_in[7];
  const float* bihb = (const float*)d_in[8];
  const float* bhhb = (const float*)d_in[9];
  const float* Wsent = (const float*)d_in[10];
  const float* bsent = (const float*)d_in[11];
  const float* wcont = (const float*)d_in[12];
  const float* bcont = (const float*)d_in[13];
  const float* Wd1 = (const float*)d_in[14];
  const float* bd1 = (const float*)d_in[15];
  const float* Wd2 = (const float*)d_in[16];
  const float* bd2 = (const float*)d_in[17];
  const float* Wsim = (const float*)d_in[18];
  const float* bias = (const float*)d_in[19];
  const float* pos_emb = (const float*)d_in[20];
  const float* pos_lin = (const float*)d_in[21];
  const float* seg_emb = (const float*)d_in[22];
  const float* seg_lin = (const float*)d_in[23];
  float* out = (float*)d_out;

  char* base = (char*)d_ws;
  size_t off = 0;
  auto alloc = [&](size_t bytes) { char* p = base + off; off += (bytes + 255) & ~255ull; return p; };
  __hip_bfloat16* xgf_b  = (__hip_bfloat16*)alloc((size_t)S_ * B_ * G3_ * 2);
  __hip_bfloat16* xgb_b  = (__hip_bfloat16*)alloc((size_t)S_ * B_ * G3_ * 2);
  char* region1          = alloc((size_t)B_ * S_ * I_ * 2);  // x_bf, later sent_b+U_b
  __hip_bfloat16* x_bf   = (__hip_bfloat16*)region1;
  __hip_bfloat16* sent_b = (__hip_bfloat16*)region1;
  __hip_bfloat16* U_b    = (__hip_bfloat16*)(region1 + (size_t)B_ * S_ * SENT_ * 2);
  __hip_bfloat16* rnn_b  = (__hip_bfloat16*)alloc((size_t)B_ * S_ * 2 * H_ * 2);
  __hip_bfloat16* Wihf_b = (__hip_bfloat16*)alloc((size_t)G3_ * I_ * 2);
  __hip_bfloat16* Wihb_b = (__hip_bfloat16*)alloc((size_t)G3_ * I_ * 2);
  __hip_bfloat16* Wpf    = (__hip_bfloat16*)alloc((size_t)G3_ * H_ * 2);
  __hip_bfloat16* Wpb    = (__hip_bfloat16*)alloc((size_t)G3_ * H_ * 2);
  __hip_bfloat16* Wsent_b= (__hip_bfloat16*)alloc((size_t)SENT_ * 2 * H_ * 2);
  __hip_bfloat16* WsimT_b= (__hip_bfloat16*)alloc((size_t)SENT_ * SENT_ * 2);
  __hip_bfloat16* h16a   = (__hip_bfloat16*)alloc(2 * (size_t)B_ * H_ * 2);  // [dir][B][H]
  __hip_bfloat16* h16b   = (__hip_bfloat16*)alloc(2 * (size_t)B_ * H_ * 2);
  unsigned int* arrive   = (unsigned int*)alloc(256 * 64 * 4);  // 256B slot per block
  float* avg             = (float*)alloc((size_t)B_ * SENT_ * 4);
  float* d1buf           = (float*)alloc((size_t)B_ * DOC_ * 4);
  float* doc             = (float*)alloc((size_t)B_ * SENT_ * 4);
  float* st              = (float*)alloc((size_t)S_ * B_ * 4);
  float* poslog          = (float*)alloc(256);
  float* segvals         = (float*)alloc(64);
  (void)ws_size;

  // fused prep: weight casts/packs, Wsim transpose, h16a+arrive zero, posseg
  prep_all<<<PREP_POS + 1, 256, 0, stream>>>(
      Wihf, Wihb, Wsent, Whhf, Whhb, Wsim, pos_emb, pos_lin, seg_emb, seg_lin,
      Wihf_b, Wihb_b, Wsent_b, Wpf, Wpb, WsimT_b, h16a, arrive, poslog, segvals);
  cast_kernel<<<(B_ * S_ * I_ / 4 + 255) / 256, 256, 0, stream>>>(x, x_bf, B_ * S_ * I_);

  mfma_xg<<<dim3(G3_ / 128, (S_ * B_) / 128, 2), 256, 0, stream>>>(x_bf, Wihf_b, bihf, Wihb_b, bihb, xgf_b, xgb_b);

  // persistent GRU scan — regular launch; 256 blocks at 1 block/CU co-resident.
  gru_persistent<<<dim3(256), dim3(256), 0, stream>>>(
      xgf_b, xgb_b, Wpf, Wpb, bhhf, bhhb, h16a, h16b, rnn_b, arrive);

  mfma_nt<1, true><<<dim3(SENT_ / 128, (B_ * S_) / 128), 256, 0, stream>>>(rnn_b, Wsent_b, bsent, sent_b, SENT_, 2 * H_);
  avg_kernel<<<B_, 256, 0, stream>>>(sent_b, ns, avg);
  gemm_nt<2><<<dim3(DOC_ / 64, B_ / 64), 256, 0, stream>>>(avg, Wd1, bd1, d1buf, DOC_, SENT_);
  gemm_nt<0><<<dim3(SENT_ / 64, B_ / 64), 256, 0, stream>>>(d1buf, Wd2, bd2, doc, SENT_, DOC_);
  static_kernel<<<B_ * S_, 64, 0, stream>>>(sent_b, doc, wcont, bcont, ns, poslog, segvals, bias, st);

  mfma_nt<0, false><<<dim3(SENT_ / 128, (B_ * S_) / 128), 256, 0, stream>>>(sent_b, WsimT_b, nullptr, U_b, SENT_, SENT_);

  novelty_all<<<B_, 256, 0, stream>>>(sent_b, U_b, st, out);
}